// Round 1
// baseline (1440.134 us; speedup 1.0000x reference)
//
#include <hip/hip_runtime.h>

#define H   128
#define RB  32
#define EPB 8

// ---------------- node encoder: h = x @ node_w + node_b, x:[N,64] ----------
__global__ __launch_bounds__(128) void node_enc(const float* __restrict__ x,
    const float* __restrict__ w, const float* __restrict__ b,
    float* __restrict__ h, int N) {
  int row = blockIdx.x;
  if (row >= N) return;
  int j = threadIdx.x;
  __shared__ float xs[64];
  if (j < 64) xs[j] = x[(size_t)row * 64 + j];
  __syncthreads();
  float acc = b[j];
#pragma unroll
  for (int k = 0; k < 64; ++k) acc = fmaf(xs[k], w[k * H + j], acc);
  h[(size_t)row * H + j] = acc;
}

// ---- fused edge encoder + message + scatter-add:
//      msg = relu(h[src] + edge_attr@edge_w + edge_b); aggr[dst] += msg ------
__global__ __launch_bounds__(128) void edge_msg(const float* __restrict__ ea,
    const float* __restrict__ ew, const float* __restrict__ eb,
    const int* __restrict__ src, const int* __restrict__ dst,
    const float* __restrict__ h, float* __restrict__ aggr, int E) {
  int e0 = blockIdx.x * EPB;
  int t = threadIdx.x;  // 0..127 = output column
  __shared__ float attr[EPB][16];
  int gidx = e0 * 16 + t;
  if (gidx < E * 16) ((float*)attr)[t] = ea[gidx];
  float wcol[16];
#pragma unroll
  for (int k = 0; k < 16; ++k) wcol[k] = ew[k * H + t];
  float bias = eb[t];
  __syncthreads();
#pragma unroll
  for (int i = 0; i < EPB; ++i) {
    int e = e0 + i;
    if (e >= E) break;
    float acc = bias;
#pragma unroll
    for (int k = 0; k < 16; ++k) acc = fmaf(attr[i][k], wcol[k], acc);
    int s = src[e], d = dst[e];
    float m = acc + h[(size_t)s * H + t];
    m = fmaxf(m, 0.0f);
    atomicAdd(&aggr[(size_t)d * H + t], m);
  }
}

// ---- GEMM1: t = (h + aggr) @ w1 + b1, plus per-column sum / sumsq ---------
__global__ __launch_bounds__(128) void mlp1(const float* __restrict__ hin,
    const float* __restrict__ aggr, const float* __restrict__ w1,
    const float* __restrict__ b1, float* __restrict__ tout,
    float* __restrict__ sum, float* __restrict__ sumsq, int N) {
  int r0 = blockIdx.x * RB;
  int j = threadIdx.x;  // output column
  __shared__ float z[RB][H];
#pragma unroll
  for (int r = 0; r < RB; ++r) {
    int g = r0 + r;
    z[r][j] = (g < N) ? (hin[(size_t)g * H + j] + aggr[(size_t)g * H + j]) : 0.0f;
  }
  __syncthreads();
  float bias = b1[j];
  float acc[RB];
#pragma unroll
  for (int r = 0; r < RB; ++r) acc[r] = bias;
#pragma unroll 2
  for (int k4 = 0; k4 < H / 4; ++k4) {
    float w0 = w1[(4 * k4 + 0) * H + j];
    float wa = w1[(4 * k4 + 1) * H + j];
    float wb = w1[(4 * k4 + 2) * H + j];
    float wc = w1[(4 * k4 + 3) * H + j];
#pragma unroll
    for (int r = 0; r < RB; ++r) {
      float4 zv = *((const float4*)&z[r][4 * k4]);
      acc[r] = fmaf(zv.x, w0, acc[r]);
      acc[r] = fmaf(zv.y, wa, acc[r]);
      acc[r] = fmaf(zv.z, wb, acc[r]);
      acc[r] = fmaf(zv.w, wc, acc[r]);
    }
  }
  int nv = N - r0; if (nv > RB) nv = RB;
  float s1 = 0.f, s2 = 0.f;
#pragma unroll
  for (int r = 0; r < RB; ++r) {
    if (r < nv) {
      tout[(size_t)(r0 + r) * H + j] = acc[r];
      s1 += acc[r];
      s2 += acc[r] * acc[r];
    }
  }
  atomicAdd(&sum[j], s1);
  atomicAdd(&sumsq[j], s2);
}

// ---- BN finalize: scale = g*rsqrt(var+eps), shift = beta - mu*scale -------
__global__ void bn_finalize(const float* __restrict__ sum,
    const float* __restrict__ sumsq, const float* __restrict__ g,
    const float* __restrict__ beta, float* __restrict__ scale,
    float* __restrict__ shift, float invN) {
  int j = threadIdx.x;
  float mu = sum[j] * invN;
  float var = sumsq[j] * invN - mu * mu;
  float inv = rsqrtf(var + 1e-5f);
  float sc = g[j] * inv;
  scale[j] = sc;
  shift[j] = beta[j] - mu * sc;
}

// ---- GEMM2: h = relu( relu(t*scale+shift) @ w2 + b2 ) ---------------------
__global__ __launch_bounds__(128) void mlp2(const float* __restrict__ tin,
    const float* __restrict__ scale, const float* __restrict__ shift,
    const float* __restrict__ w2, const float* __restrict__ b2,
    float* __restrict__ hout, int N) {
  int r0 = blockIdx.x * RB;
  int j = threadIdx.x;
  __shared__ float z[RB][H];
  float sc = scale[j], sh = shift[j];
#pragma unroll
  for (int r = 0; r < RB; ++r) {
    int g = r0 + r;
    float v = (g < N) ? tin[(size_t)g * H + j] : 0.0f;
    z[r][j] = fmaxf(fmaf(v, sc, sh), 0.0f);
  }
  __syncthreads();
  float bias = b2[j];
  float acc[RB];
#pragma unroll
  for (int r = 0; r < RB; ++r) acc[r] = bias;
#pragma unroll 2
  for (int k4 = 0; k4 < H / 4; ++k4) {
    float w0 = w2[(4 * k4 + 0) * H + j];
    float wa = w2[(4 * k4 + 1) * H + j];
    float wb = w2[(4 * k4 + 2) * H + j];
    float wc = w2[(4 * k4 + 3) * H + j];
#pragma unroll
    for (int r = 0; r < RB; ++r) {
      float4 zv = *((const float4*)&z[r][4 * k4]);
      acc[r] = fmaf(zv.x, w0, acc[r]);
      acc[r] = fmaf(zv.y, wa, acc[r]);
      acc[r] = fmaf(zv.z, wb, acc[r]);
      acc[r] = fmaf(zv.w, wc, acc[r]);
    }
  }
  int nv = N - r0; if (nv > RB) nv = RB;
#pragma unroll
  for (int r = 0; r < RB; ++r) {
    if (r < nv) hout[(size_t)(r0 + r) * H + j] = fmaxf(acc[r], 0.0f);
  }
}

// ---- global_add_pool via atomics (batch is sorted but treat generally) ----
__global__ __launch_bounds__(128) void pool_kernel(const float* __restrict__ h,
    const int* __restrict__ batch, float* __restrict__ pooled, int N) {
  int r0 = blockIdx.x * 8;
  int j = threadIdx.x;
#pragma unroll
  for (int i = 0; i < 8; ++i) {
    int n = r0 + i;
    if (n >= N) break;
    atomicAdd(&pooled[(size_t)batch[n] * H + j], h[(size_t)n * H + j]);
  }
}

// ---- final FC: out = pooled @ fc_w + fc_b ---------------------------------
__global__ __launch_bounds__(128) void fc_kernel(const float* __restrict__ pooled,
    const float* __restrict__ w, const float* __restrict__ b,
    float* __restrict__ out, int C) {
  int g = blockIdx.x;
  int j = threadIdx.x;
  __shared__ float p[H];
  p[j] = pooled[(size_t)g * H + j];
  __syncthreads();
  if (j < C) {
    float acc = b[j];
#pragma unroll 4
    for (int k = 0; k < H; ++k) acc = fmaf(p[k], w[k * C + j], acc);
    out[(size_t)g * C + j] = acc;
  }
}

extern "C" void kernel_launch(void* const* d_in, const int* in_sizes, int n_in,
                              void* d_out, int out_size, void* d_ws, size_t ws_size,
                              hipStream_t stream) {
  const float* x         = (const float*)d_in[0];
  const float* edge_attr = (const float*)d_in[1];
  const float* node_w    = (const float*)d_in[2];
  const float* node_b    = (const float*)d_in[3];
  const float* edge_w    = (const float*)d_in[4];
  const float* edge_b    = (const float*)d_in[5];
  const float* lin1_w    = (const float*)d_in[6];
  const float* lin1_b    = (const float*)d_in[7];
  const float* bn_g      = (const float*)d_in[8];
  const float* bn_b      = (const float*)d_in[9];
  const float* lin2_w    = (const float*)d_in[10];
  const float* lin2_b    = (const float*)d_in[11];
  const float* fc_w      = (const float*)d_in[12];
  const float* fc_b      = (const float*)d_in[13];
  const int*   edge_index= (const int*)d_in[14];
  const int*   batch     = (const int*)d_in[15];

  int N = in_sizes[0] / 64;       // 50000
  int E = in_sizes[1] / 16;       // 640000
  int C = in_sizes[13];           // 10
  int G = out_size / C;           // 512

  const int* src = edge_index;
  const int* dst = edge_index + E;

  float* ws     = (float*)d_ws;
  float* h      = ws;
  float* aggr   = h    + (size_t)N * H;
  float* t      = aggr + (size_t)N * H;
  float* pooled = t    + (size_t)N * H;
  float* sums   = pooled + (size_t)G * H;   // [H] sum, then [H] sumsq
  float* sumsq  = sums + H;
  float* scale  = sumsq + H;
  float* shift  = scale + H;

  node_enc<<<N, 128, 0, stream>>>(x, node_w, node_b, h, N);

  int nblk = (N + RB - 1) / RB;
  int eblk = (E + EPB - 1) / EPB;
  for (int l = 0; l < 3; ++l) {
    hipMemsetAsync(aggr, 0, (size_t)N * H * sizeof(float), stream);
    hipMemsetAsync(sums, 0, 2 * H * sizeof(float), stream);
    edge_msg<<<eblk, 128, 0, stream>>>(edge_attr, edge_w, edge_b, src, dst, h, aggr, E);
    mlp1<<<nblk, 128, 0, stream>>>(h, aggr, lin1_w + (size_t)l * H * H,
                                   lin1_b + (size_t)l * H, t, sums, sumsq, N);
    bn_finalize<<<1, H, 0, stream>>>(sums, sumsq, bn_g + (size_t)l * H,
                                     bn_b + (size_t)l * H, scale, shift, 1.0f / N);
    mlp2<<<nblk, 128, 0, stream>>>(t, scale, shift, lin2_w + (size_t)l * H * H,
                                   lin2_b + (size_t)l * H, h, N);
  }

  hipMemsetAsync(pooled, 0, (size_t)G * H * sizeof(float), stream);
  pool_kernel<<<(N + 7) / 8, 128, 0, stream>>>(h, batch, pooled, N);
  fc_kernel<<<G, 128, 0, stream>>>(pooled, fc_w, fc_b, (float*)d_out, C);
}

// Round 2
// 1045.998 us; speedup vs baseline: 1.3768x; 1.3768x over previous
//
#include <hip/hip_runtime.h>

#define H     128
#define RB    32
#define CHUNK 32

// ---------------- node encoder: h = x @ node_w + node_b, x:[N,64] ----------
__global__ __launch_bounds__(128) void node_enc(const float* __restrict__ x,
    const float* __restrict__ w, const float* __restrict__ b,
    float* __restrict__ h, int N) {
  int row = blockIdx.x;
  if (row >= N) return;
  int j = threadIdx.x;
  __shared__ float xs[64];
  if (j < 64) xs[j] = x[(size_t)row * 64 + j];
  __syncthreads();
  float acc = b[j];
#pragma unroll
  for (int k = 0; k < 64; ++k) acc = fmaf(xs[k], w[k * H + j], acc);
  h[(size_t)row * H + j] = acc;
}

// ---------------- CSR build: degree count ----------------------------------
__global__ __launch_bounds__(256) void count_deg(const int* __restrict__ dst,
    int* __restrict__ cnt, int E) {
  int e = blockIdx.x * 256 + threadIdx.x;
  if (e < E) atomicAdd(&cnt[dst[e]], 1);
}

// ---------------- CSR build: 1-block scan of degrees -> offsets, cursor ----
__global__ __launch_bounds__(1024) void scan_deg(const int* __restrict__ cnt,
    int* __restrict__ off, int* __restrict__ cursor, int N) {
  __shared__ int part[1024];
  int t = threadIdx.x;
  int per = (N + 1023) / 1024;
  int b = t * per;
  int s = 0;
  for (int i = 0; i < per; ++i) { int idx = b + i; if (idx < N) s += cnt[idx]; }
  part[t] = s;
  __syncthreads();
  // Hillis-Steele inclusive scan
  for (int o = 1; o < 1024; o <<= 1) {
    int v = (t >= o) ? part[t - o] : 0;
    __syncthreads();
    part[t] += v;
    __syncthreads();
  }
  int run = part[t] - s;  // exclusive prefix
  for (int i = 0; i < per; ++i) {
    int idx = b + i;
    if (idx < N) { off[idx] = run; cursor[idx] = run; run += cnt[idx]; }
  }
  if (t == 1023) off[N] = part[1023];
}

// ---------------- CSR build: scatter edge ids into buckets -----------------
__global__ __launch_bounds__(256) void scatter_csr(const int* __restrict__ src,
    const int* __restrict__ dst, int* __restrict__ cursor,
    int* __restrict__ perm, int* __restrict__ src_perm, int E) {
  int e = blockIdx.x * 256 + threadIdx.x;
  if (e < E) {
    int pos = atomicAdd(&cursor[dst[e]], 1);
    perm[pos] = e;
    src_perm[pos] = src[e];
  }
}

// ---- CSR aggregation: z[n] = h[n] + sum_{e->n} relu(h[src]+ea[e]@ew+eb) ---
__global__ __launch_bounds__(128) void aggr_csr(const float* __restrict__ ea,
    const float* __restrict__ ew, const float* __restrict__ eb,
    const int* __restrict__ perm, const int* __restrict__ src_perm,
    const int* __restrict__ off, const float* __restrict__ h,
    float* __restrict__ z, int N) {
  int n = blockIdx.x;
  int j = threadIdx.x;
  int beg = off[n], end = off[n + 1];
  float wcol[16];
#pragma unroll
  for (int k = 0; k < 16; ++k) wcol[k] = ew[k * H + j];
  float bias = eb[j];
  float acc = 0.f;
  __shared__ float attr[CHUNK][16];
  __shared__ int ssrc[CHUNK];
  __shared__ int pe[CHUNK];
  int sub = j >> 4, lane16 = j & 15;
  for (int c0 = beg; c0 < end; c0 += CHUNK) {
    int cnt = min(CHUNK, end - c0);
    if (j < cnt) { pe[j] = perm[c0 + j]; ssrc[j] = src_perm[c0 + j]; }
    __syncthreads();
    for (int i0 = 0; i0 < cnt; i0 += 8) {
      int ii = i0 + sub;
      if (ii < cnt) attr[ii][lane16] = ea[(size_t)pe[ii] * 16 + lane16];
    }
    __syncthreads();
    for (int i = 0; i < cnt; ++i) {
      float enc = bias;
#pragma unroll
      for (int k = 0; k < 16; ++k) enc = fmaf(attr[i][k], wcol[k], enc);
      float m = enc + h[(size_t)ssrc[i] * H + j];
      acc += fmaxf(m, 0.f);
    }
    __syncthreads();
  }
  z[(size_t)n * H + j] = h[(size_t)n * H + j] + acc;
}

// ---- GEMM1: t = z @ w1 + b1 (in-place over z), plus column sum/sumsq ------
__global__ __launch_bounds__(128) void mlp1(const float* __restrict__ zin,
    const float* __restrict__ w1, const float* __restrict__ b1,
    float* __restrict__ tout, float* __restrict__ sum,
    float* __restrict__ sumsq, int N) {
  int r0 = blockIdx.x * RB;
  int j = threadIdx.x;
  __shared__ float z[RB][H];
#pragma unroll
  for (int r = 0; r < RB; ++r) {
    int g = r0 + r;
    z[r][j] = (g < N) ? zin[(size_t)g * H + j] : 0.0f;
  }
  __syncthreads();
  float bias = b1[j];
  float acc[RB];
#pragma unroll
  for (int r = 0; r < RB; ++r) acc[r] = bias;
#pragma unroll 2
  for (int k4 = 0; k4 < H / 4; ++k4) {
    float w0 = w1[(4 * k4 + 0) * H + j];
    float wa = w1[(4 * k4 + 1) * H + j];
    float wb = w1[(4 * k4 + 2) * H + j];
    float wc = w1[(4 * k4 + 3) * H + j];
#pragma unroll
    for (int r = 0; r < RB; ++r) {
      float4 zv = *((const float4*)&z[r][4 * k4]);
      acc[r] = fmaf(zv.x, w0, acc[r]);
      acc[r] = fmaf(zv.y, wa, acc[r]);
      acc[r] = fmaf(zv.z, wb, acc[r]);
      acc[r] = fmaf(zv.w, wc, acc[r]);
    }
  }
  int nv = N - r0; if (nv > RB) nv = RB;
  float s1 = 0.f, s2 = 0.f;
#pragma unroll
  for (int r = 0; r < RB; ++r) {
    if (r < nv) {
      tout[(size_t)(r0 + r) * H + j] = acc[r];
      s1 += acc[r];
      s2 += acc[r] * acc[r];
    }
  }
  atomicAdd(&sum[j], s1);
  atomicAdd(&sumsq[j], s2);
}

// ---- BN finalize ----------------------------------------------------------
__global__ void bn_finalize(const float* __restrict__ sum,
    const float* __restrict__ sumsq, const float* __restrict__ g,
    const float* __restrict__ beta, float* __restrict__ scale,
    float* __restrict__ shift, float invN) {
  int j = threadIdx.x;
  float mu = sum[j] * invN;
  float var = sumsq[j] * invN - mu * mu;
  float inv = rsqrtf(var + 1e-5f);
  float sc = g[j] * inv;
  scale[j] = sc;
  shift[j] = beta[j] - mu * sc;
}

// ---- GEMM2: h = relu( relu(t*scale+shift) @ w2 + b2 ), optional pool ------
__global__ __launch_bounds__(128) void mlp2(const float* __restrict__ tin,
    const float* __restrict__ scale, const float* __restrict__ shift,
    const float* __restrict__ w2, const float* __restrict__ b2,
    float* __restrict__ hout, int N,
    const int* __restrict__ batch, float* __restrict__ pooled) {
  int r0 = blockIdx.x * RB;
  int j = threadIdx.x;
  __shared__ float z[RB][H];
  float sc = scale[j], sh = shift[j];
#pragma unroll
  for (int r = 0; r < RB; ++r) {
    int g = r0 + r;
    float v = (g < N) ? tin[(size_t)g * H + j] : 0.0f;
    z[r][j] = fmaxf(fmaf(v, sc, sh), 0.0f);
  }
  __syncthreads();
  float bias = b2[j];
  float acc[RB];
#pragma unroll
  for (int r = 0; r < RB; ++r) acc[r] = bias;
#pragma unroll 2
  for (int k4 = 0; k4 < H / 4; ++k4) {
    float w0 = w2[(4 * k4 + 0) * H + j];
    float wa = w2[(4 * k4 + 1) * H + j];
    float wb = w2[(4 * k4 + 2) * H + j];
    float wc = w2[(4 * k4 + 3) * H + j];
#pragma unroll
    for (int r = 0; r < RB; ++r) {
      float4 zv = *((const float4*)&z[r][4 * k4]);
      acc[r] = fmaf(zv.x, w0, acc[r]);
      acc[r] = fmaf(zv.y, wa, acc[r]);
      acc[r] = fmaf(zv.z, wb, acc[r]);
      acc[r] = fmaf(zv.w, wc, acc[r]);
    }
  }
  int nv = N - r0; if (nv > RB) nv = RB;
#pragma unroll
  for (int r = 0; r < RB; ++r) {
    if (r < nv) {
      acc[r] = fmaxf(acc[r], 0.0f);
      hout[(size_t)(r0 + r) * H + j] = acc[r];
    }
  }
  if (pooled != nullptr) {
    // sorted batch: run-length flush to minimize atomics
    int curb = batch[r0];
    float pa = 0.f;
    for (int r = 0; r < nv; ++r) {
      int bb = batch[r0 + r];
      if (bb != curb) {
        atomicAdd(&pooled[(size_t)curb * H + j], pa);
        pa = 0.f;
        curb = bb;
      }
      pa += acc[r];
    }
    atomicAdd(&pooled[(size_t)curb * H + j], pa);
  }
}

// ---- final FC: out = pooled @ fc_w + fc_b ---------------------------------
__global__ __launch_bounds__(128) void fc_kernel(const float* __restrict__ pooled,
    const float* __restrict__ w, const float* __restrict__ b,
    float* __restrict__ out, int C) {
  int g = blockIdx.x;
  int j = threadIdx.x;
  __shared__ float p[H];
  p[j] = pooled[(size_t)g * H + j];
  __syncthreads();
  if (j < C) {
    float acc = b[j];
#pragma unroll 4
    for (int k = 0; k < H; ++k) acc = fmaf(p[k], w[k * C + j], acc);
    out[(size_t)g * C + j] = acc;
  }
}

extern "C" void kernel_launch(void* const* d_in, const int* in_sizes, int n_in,
                              void* d_out, int out_size, void* d_ws, size_t ws_size,
                              hipStream_t stream) {
  const float* x         = (const float*)d_in[0];
  const float* edge_attr = (const float*)d_in[1];
  const float* node_w    = (const float*)d_in[2];
  const float* node_b    = (const float*)d_in[3];
  const float* edge_w    = (const float*)d_in[4];
  const float* edge_b    = (const float*)d_in[5];
  const float* lin1_w    = (const float*)d_in[6];
  const float* lin1_b    = (const float*)d_in[7];
  const float* bn_g      = (const float*)d_in[8];
  const float* bn_b      = (const float*)d_in[9];
  const float* lin2_w    = (const float*)d_in[10];
  const float* lin2_b    = (const float*)d_in[11];
  const float* fc_w      = (const float*)d_in[12];
  const float* fc_b      = (const float*)d_in[13];
  const int*   edge_index= (const int*)d_in[14];
  const int*   batch     = (const int*)d_in[15];

  int N = in_sizes[0] / 64;       // 50000
  int E = in_sizes[1] / 16;       // 640000
  int C = in_sizes[13];           // 10
  int G = out_size / C;           // 512

  const int* src = edge_index;
  const int* dst = edge_index + E;

  float* ws     = (float*)d_ws;
  float* h      = ws;                       // [N,H]
  float* zt     = h + (size_t)N * H;        // [N,H] shared by z and t (aliased in-place)
  float* pooled = zt + (size_t)N * H;       // [G,H]
  float* sums   = pooled + (size_t)G * H;   // [H]
  float* sumsq  = sums + H;                 // [H]
  float* scale  = sumsq + H;                // [H]
  float* shift  = scale + H;                // [H]
  int*   cnt      = (int*)(shift + H);      // [N]
  int*   off      = cnt + N;                // [N+1]
  int*   cursor   = off + N + 1;            // [N]
  int*   perm     = cursor + N;             // [E]
  int*   src_perm = perm + E;               // [E]

  // --- one-time CSR build (runs every launch; deterministic work) ---
  hipMemsetAsync(cnt, 0, (size_t)N * sizeof(int), stream);
  count_deg<<<(E + 255) / 256, 256, 0, stream>>>(dst, cnt, E);
  scan_deg<<<1, 1024, 0, stream>>>(cnt, off, cursor, N);
  scatter_csr<<<(E + 255) / 256, 256, 0, stream>>>(src, dst, cursor, perm, src_perm, E);

  node_enc<<<N, 128, 0, stream>>>(x, node_w, node_b, h, N);

  int nblk = (N + RB - 1) / RB;
  for (int l = 0; l < 3; ++l) {
    hipMemsetAsync(sums, 0, 2 * H * sizeof(float), stream);
    aggr_csr<<<N, 128, 0, stream>>>(edge_attr, edge_w, edge_b, perm, src_perm,
                                    off, h, zt, N);
    mlp1<<<nblk, 128, 0, stream>>>(zt, lin1_w + (size_t)l * H * H,
                                   lin1_b + (size_t)l * H, zt, sums, sumsq, N);
    bn_finalize<<<1, H, 0, stream>>>(sums, sumsq, bn_g + (size_t)l * H,
                                     bn_b + (size_t)l * H, scale, shift, 1.0f / N);
    bool last = (l == 2);
    if (last) hipMemsetAsync(pooled, 0, (size_t)G * H * sizeof(float), stream);
    mlp2<<<nblk, 128, 0, stream>>>(zt, scale, shift, lin2_w + (size_t)l * H * H,
                                   lin2_b + (size_t)l * H, h, N,
                                   batch, last ? pooled : nullptr);
  }

  fc_kernel<<<G, 128, 0, stream>>>(pooled, fc_w, fc_b, (float*)d_out, C);
}

// Round 3
// 1039.857 us; speedup vs baseline: 1.3849x; 1.0059x over previous
//
#include <hip/hip_runtime.h>

#define H     128
#define RB    32
#define CHUNK 32
#define NPB   8

// ---------------- node encoder: h = x @ node_w + node_b, x:[N,64] ----------
__global__ __launch_bounds__(128) void node_enc(const float* __restrict__ x,
    const float* __restrict__ w, const float* __restrict__ b,
    float* __restrict__ h, int N) {
  int row = blockIdx.x;
  if (row >= N) return;
  int j = threadIdx.x;
  __shared__ float xs[64];
  if (j < 64) xs[j] = x[(size_t)row * 64 + j];
  __syncthreads();
  float acc = b[j];
#pragma unroll
  for (int k = 0; k < 64; ++k) acc = fmaf(xs[k], w[k * H + j], acc);
  h[(size_t)row * H + j] = acc;
}

// ---------------- CSR build: degree count ----------------------------------
__global__ __launch_bounds__(256) void count_deg(const int* __restrict__ dst,
    int* __restrict__ cnt, int E) {
  int e = blockIdx.x * 256 + threadIdx.x;
  if (e < E) atomicAdd(&cnt[dst[e]], 1);
}

// ---------------- scan pass 1: per-block (256-elem) sums -------------------
__global__ __launch_bounds__(256) void block_sum(const int* __restrict__ cnt,
    int* __restrict__ bsum, int N) {
  int t = threadIdx.x;
  int i = blockIdx.x * 256 + t;
  int v = (i < N) ? cnt[i] : 0;
#pragma unroll
  for (int o = 32; o > 0; o >>= 1) v += __shfl_down(v, o, 64);
  __shared__ int wt[4];
  if ((t & 63) == 0) wt[t >> 6] = v;
  __syncthreads();
  if (t == 0) bsum[blockIdx.x] = wt[0] + wt[1] + wt[2] + wt[3];
}

// ---------------- scan pass 2: 1-block scan of block sums (nb <= 1024) -----
__global__ __launch_bounds__(1024) void scan_bsum(const int* __restrict__ bsum,
    int* __restrict__ bbase, int nb) {
  __shared__ int s[1024];
  int t = threadIdx.x;
  int v = (t < nb) ? bsum[t] : 0;
  s[t] = v;
  __syncthreads();
  for (int o = 1; o < 1024; o <<= 1) {
    int u = (t >= o) ? s[t - o] : 0;
    __syncthreads();
    s[t] += u;
    __syncthreads();
  }
  if (t < nb) bbase[t] = s[t] - v;  // exclusive
}

// ---------------- scan pass 3: in-block scan + base -> off, cursor ---------
__global__ __launch_bounds__(256) void scan_pass(const int* __restrict__ cnt,
    const int* __restrict__ bbase, int* __restrict__ off,
    int* __restrict__ cursor, int N) {
  int t = threadIdx.x;
  int i = blockIdx.x * 256 + t;
  int v = (i < N) ? cnt[i] : 0;
  int lane = t & 63;
  int incl = v;
#pragma unroll
  for (int o = 1; o < 64; o <<= 1) {
    int u = __shfl_up(incl, o, 64);
    if (lane >= o) incl += u;
  }
  __shared__ int wtot[4];
  int w = t >> 6;
  if (lane == 63) wtot[w] = incl;
  __syncthreads();
  if (t == 0) {
    int run = 0;
#pragma unroll
    for (int k = 0; k < 4; ++k) { int tmp = wtot[k]; wtot[k] = run; run += tmp; }
  }
  __syncthreads();
  int excl = incl - v + wtot[w] + bbase[blockIdx.x];
  if (i < N) { off[i] = excl; cursor[i] = excl; }
  if (i == N - 1) off[N] = excl + v;
}

// ---------------- CSR build: scatter edge ids into buckets -----------------
__global__ __launch_bounds__(256) void scatter_csr(const int* __restrict__ src,
    const int* __restrict__ dst, int* __restrict__ cursor,
    int* __restrict__ perm, int* __restrict__ src_perm, int E) {
  int e = blockIdx.x * 256 + threadIdx.x;
  if (e < E) {
    int pos = atomicAdd(&cursor[dst[e]], 1);
    perm[pos] = e;
    src_perm[pos] = src[e];
  }
}

// ---- CSR aggregation: z[n] = h[n] + sum_{e->n} relu(h[src]+ea[e]@ew+eb) ---
__global__ __launch_bounds__(128) void aggr_csr(const float* __restrict__ ea,
    const float* __restrict__ ew, const float* __restrict__ eb,
    const int* __restrict__ perm, const int* __restrict__ src_perm,
    const int* __restrict__ off, const float* __restrict__ h,
    float* __restrict__ z, int N) {
  int j = threadIdx.x;
  float wcol[16];
#pragma unroll
  for (int k = 0; k < 16; ++k) wcol[k] = ew[k * H + j];
  float bias = eb[j];
  __shared__ float attr[CHUNK][16];
  __shared__ int ssrc[CHUNK];
  __shared__ int pe[CHUNK];
  int sub = j >> 4, lane16 = j & 15;
  int n0 = blockIdx.x * NPB;
  for (int p = 0; p < NPB; ++p) {
    int n = n0 + p;
    if (n >= N) break;
    int beg = off[n], end = off[n + 1];
    float acc = 0.f;
    for (int c0 = beg; c0 < end; c0 += CHUNK) {
      int cnt = min(CHUNK, end - c0);
      if (j < cnt) { pe[j] = perm[c0 + j]; ssrc[j] = src_perm[c0 + j]; }
      __syncthreads();
      for (int i0 = 0; i0 < cnt; i0 += 8) {
        int ii = i0 + sub;
        if (ii < cnt) attr[ii][lane16] = ea[(size_t)pe[ii] * 16 + lane16];
      }
      __syncthreads();
      for (int i = 0; i < cnt; ++i) {
        float enc = bias;
#pragma unroll
        for (int k = 0; k < 16; ++k) enc = fmaf(attr[i][k], wcol[k], enc);
        float m = enc + h[(size_t)ssrc[i] * H + j];
        acc += fmaxf(m, 0.f);
      }
      __syncthreads();
    }
    z[(size_t)n * H + j] = h[(size_t)n * H + j] + acc;
  }
}

// ---- GEMM1: t = z @ w1 + b1 (in-place over z), plus column sum/sumsq ------
__global__ __launch_bounds__(128) void mlp1(const float* __restrict__ zin,
    const float* __restrict__ w1, const float* __restrict__ b1,
    float* __restrict__ tout, float* __restrict__ sum,
    float* __restrict__ sumsq, int N) {
  int r0 = blockIdx.x * RB;
  int j = threadIdx.x;
  __shared__ float z[RB][H];
#pragma unroll
  for (int r = 0; r < RB; ++r) {
    int g = r0 + r;
    z[r][j] = (g < N) ? zin[(size_t)g * H + j] : 0.0f;
  }
  __syncthreads();
  float bias = b1[j];
  float acc[RB];
#pragma unroll
  for (int r = 0; r < RB; ++r) acc[r] = bias;
#pragma unroll 2
  for (int k4 = 0; k4 < H / 4; ++k4) {
    float w0 = w1[(4 * k4 + 0) * H + j];
    float wa = w1[(4 * k4 + 1) * H + j];
    float wb = w1[(4 * k4 + 2) * H + j];
    float wc = w1[(4 * k4 + 3) * H + j];
#pragma unroll
    for (int r = 0; r < RB; ++r) {
      float4 zv = *((const float4*)&z[r][4 * k4]);
      acc[r] = fmaf(zv.x, w0, acc[r]);
      acc[r] = fmaf(zv.y, wa, acc[r]);
      acc[r] = fmaf(zv.z, wb, acc[r]);
      acc[r] = fmaf(zv.w, wc, acc[r]);
    }
  }
  int nv = N - r0; if (nv > RB) nv = RB;
  float s1 = 0.f, s2 = 0.f;
#pragma unroll
  for (int r = 0; r < RB; ++r) {
    if (r < nv) {
      tout[(size_t)(r0 + r) * H + j] = acc[r];
      s1 += acc[r];
      s2 += acc[r] * acc[r];
    }
  }
  atomicAdd(&sum[j], s1);
  atomicAdd(&sumsq[j], s2);
}

// ---- BN finalize ----------------------------------------------------------
__global__ void bn_finalize(const float* __restrict__ sum,
    const float* __restrict__ sumsq, const float* __restrict__ g,
    const float* __restrict__ beta, float* __restrict__ scale,
    float* __restrict__ shift, float invN) {
  int j = threadIdx.x;
  float mu = sum[j] * invN;
  float var = sumsq[j] * invN - mu * mu;
  float inv = rsqrtf(var + 1e-5f);
  float sc = g[j] * inv;
  scale[j] = sc;
  shift[j] = beta[j] - mu * sc;
}

// ---- GEMM2: h = relu( relu(t*scale+shift) @ w2 + b2 ), optional pool ------
__global__ __launch_bounds__(128) void mlp2(const float* __restrict__ tin,
    const float* __restrict__ scale, const float* __restrict__ shift,
    const float* __restrict__ w2, const float* __restrict__ b2,
    float* __restrict__ hout, int N,
    const int* __restrict__ batch, float* __restrict__ pooled) {
  int r0 = blockIdx.x * RB;
  int j = threadIdx.x;
  __shared__ float z[RB][H];
  float sc = scale[j], sh = shift[j];
#pragma unroll
  for (int r = 0; r < RB; ++r) {
    int g = r0 + r;
    float v = (g < N) ? tin[(size_t)g * H + j] : 0.0f;
    z[r][j] = fmaxf(fmaf(v, sc, sh), 0.0f);
  }
  __syncthreads();
  float bias = b2[j];
  float acc[RB];
#pragma unroll
  for (int r = 0; r < RB; ++r) acc[r] = bias;
#pragma unroll 2
  for (int k4 = 0; k4 < H / 4; ++k4) {
    float w0 = w2[(4 * k4 + 0) * H + j];
    float wa = w2[(4 * k4 + 1) * H + j];
    float wb = w2[(4 * k4 + 2) * H + j];
    float wc = w2[(4 * k4 + 3) * H + j];
#pragma unroll
    for (int r = 0; r < RB; ++r) {
      float4 zv = *((const float4*)&z[r][4 * k4]);
      acc[r] = fmaf(zv.x, w0, acc[r]);
      acc[r] = fmaf(zv.y, wa, acc[r]);
      acc[r] = fmaf(zv.z, wb, acc[r]);
      acc[r] = fmaf(zv.w, wc, acc[r]);
    }
  }
  int nv = N - r0; if (nv > RB) nv = RB;
#pragma unroll
  for (int r = 0; r < RB; ++r) {
    if (r < nv) {
      acc[r] = fmaxf(acc[r], 0.0f);
      hout[(size_t)(r0 + r) * H + j] = acc[r];
    }
  }
  if (pooled != nullptr) {
    int curb = batch[r0];
    float pa = 0.f;
    for (int r = 0; r < nv; ++r) {
      int bb = batch[r0 + r];
      if (bb != curb) {
        atomicAdd(&pooled[(size_t)curb * H + j], pa);
        pa = 0.f;
        curb = bb;
      }
      pa += acc[r];
    }
    atomicAdd(&pooled[(size_t)curb * H + j], pa);
  }
}

// ---- final FC: out = pooled @ fc_w + fc_b ---------------------------------
__global__ __launch_bounds__(128) void fc_kernel(const float* __restrict__ pooled,
    const float* __restrict__ w, const float* __restrict__ b,
    float* __restrict__ out, int C) {
  int g = blockIdx.x;
  int j = threadIdx.x;
  __shared__ float p[H];
  p[j] = pooled[(size_t)g * H + j];
  __syncthreads();
  if (j < C) {
    float acc = b[j];
#pragma unroll 4
    for (int k = 0; k < H; ++k) acc = fmaf(p[k], w[k * C + j], acc);
    out[(size_t)g * C + j] = acc;
  }
}

extern "C" void kernel_launch(void* const* d_in, const int* in_sizes, int n_in,
                              void* d_out, int out_size, void* d_ws, size_t ws_size,
                              hipStream_t stream) {
  const float* x         = (const float*)d_in[0];
  const float* edge_attr = (const float*)d_in[1];
  const float* node_w    = (const float*)d_in[2];
  const float* node_b    = (const float*)d_in[3];
  const float* edge_w    = (const float*)d_in[4];
  const float* edge_b    = (const float*)d_in[5];
  const float* lin1_w    = (const float*)d_in[6];
  const float* lin1_b    = (const float*)d_in[7];
  const float* bn_g      = (const float*)d_in[8];
  const float* bn_b      = (const float*)d_in[9];
  const float* lin2_w    = (const float*)d_in[10];
  const float* lin2_b    = (const float*)d_in[11];
  const float* fc_w      = (const float*)d_in[12];
  const float* fc_b      = (const float*)d_in[13];
  const int*   edge_index= (const int*)d_in[14];
  const int*   batch     = (const int*)d_in[15];

  int N = in_sizes[0] / 64;       // 50000
  int E = in_sizes[1] / 16;       // 640000
  int C = in_sizes[13];           // 10
  int G = out_size / C;           // 512

  const int* src = edge_index;
  const int* dst = edge_index + E;

  float* ws     = (float*)d_ws;
  float* h      = ws;                       // [N,H]
  float* zt     = h + (size_t)N * H;        // [N,H] z and t aliased in-place
  float* pooled = zt + (size_t)N * H;       // [G,H]
  float* sums   = pooled + (size_t)G * H;   // [H]
  float* sumsq  = sums + H;                 // [H]
  float* scale  = sumsq + H;                // [H]
  float* shift  = scale + H;                // [H]
  int*   cnt      = (int*)(shift + H);      // [N]
  int*   off      = cnt + N;                // [N+1]
  int*   cursor   = off + N + 1;            // [N]
  int*   perm     = cursor + N;             // [E]
  int*   src_perm = perm + E;               // [E]
  int*   bsum     = src_perm + E;           // [nb]
  int*   bbase    = bsum + 1024;            // [nb]

  int nb = (N + 255) / 256;                 // 196 <= 1024

  // --- CSR build (every launch; deterministic) ---
  hipMemsetAsync(cnt, 0, (size_t)N * sizeof(int), stream);
  count_deg<<<(E + 255) / 256, 256, 0, stream>>>(dst, cnt, E);
  block_sum<<<nb, 256, 0, stream>>>(cnt, bsum, N);
  scan_bsum<<<1, 1024, 0, stream>>>(bsum, bbase, nb);
  scan_pass<<<nb, 256, 0, stream>>>(cnt, bbase, off, cursor, N);
  scatter_csr<<<(E + 255) / 256, 256, 0, stream>>>(src, dst, cursor, perm, src_perm, E);

  node_enc<<<N, 128, 0, stream>>>(x, node_w, node_b, h, N);

  int nblk = (N + RB - 1) / RB;
  int ablk = (N + NPB - 1) / NPB;
  for (int l = 0; l < 3; ++l) {
    hipMemsetAsync(sums, 0, 2 * H * sizeof(float), stream);
    aggr_csr<<<ablk, 128, 0, stream>>>(edge_attr, edge_w, edge_b, perm, src_perm,
                                       off, h, zt, N);
    mlp1<<<nblk, 128, 0, stream>>>(zt, lin1_w + (size_t)l * H * H,
                                   lin1_b + (size_t)l * H, zt, sums, sumsq, N);
    bn_finalize<<<1, H, 0, stream>>>(sums, sumsq, bn_g + (size_t)l * H,
                                     bn_b + (size_t)l * H, scale, shift, 1.0f / N);
    bool last = (l == 2);
    if (last) hipMemsetAsync(pooled, 0, (size_t)G * H * sizeof(float), stream);
    mlp2<<<nblk, 128, 0, stream>>>(zt, scale, shift, lin2_w + (size_t)l * H * H,
                                   lin2_b + (size_t)l * H, h, N,
                                   batch, last ? pooled : nullptr);
  }

  fc_kernel<<<G, 128, 0, stream>>>(pooled, fc_w, fc_b, (float*)d_out, C);
}

// Round 4
// 940.069 us; speedup vs baseline: 1.5319x; 1.1062x over previous
//
#include <hip/hip_runtime.h>

#define H     128
#define RB    32

// ---------------- node encoder: h = x @ node_w + node_b, x:[N,64] ----------
__global__ __launch_bounds__(128) void node_enc(const float* __restrict__ x,
    const float* __restrict__ w, const float* __restrict__ b,
    float* __restrict__ h, int N) {
  int row = blockIdx.x;
  if (row >= N) return;
  int j = threadIdx.x;
  __shared__ float xs[64];
  if (j < 64) xs[j] = x[(size_t)row * 64 + j];
  __syncthreads();
  float acc = b[j];
#pragma unroll
  for (int k = 0; k < 64; ++k) acc = fmaf(xs[k], w[k * H + j], acc);
  h[(size_t)row * H + j] = acc;
}

// ---------------- CSR build: degree count ----------------------------------
__global__ __launch_bounds__(256) void count_deg(const int* __restrict__ dst,
    int* __restrict__ cnt, int E) {
  int e = blockIdx.x * 256 + threadIdx.x;
  if (e < E) atomicAdd(&cnt[dst[e]], 1);
}

// ---------------- scan pass 1: per-block (256-elem) sums -------------------
__global__ __launch_bounds__(256) void block_sum(const int* __restrict__ cnt,
    int* __restrict__ bsum, int N) {
  int t = threadIdx.x;
  int i = blockIdx.x * 256 + t;
  int v = (i < N) ? cnt[i] : 0;
#pragma unroll
  for (int o = 32; o > 0; o >>= 1) v += __shfl_down(v, o, 64);
  __shared__ int wt[4];
  if ((t & 63) == 0) wt[t >> 6] = v;
  __syncthreads();
  if (t == 0) bsum[blockIdx.x] = wt[0] + wt[1] + wt[2] + wt[3];
}

// ---------------- scan pass 2: 1-block scan of block sums (nb <= 1024) -----
__global__ __launch_bounds__(1024) void scan_bsum(const int* __restrict__ bsum,
    int* __restrict__ bbase, int nb) {
  __shared__ int s[1024];
  int t = threadIdx.x;
  int v = (t < nb) ? bsum[t] : 0;
  s[t] = v;
  __syncthreads();
  for (int o = 1; o < 1024; o <<= 1) {
    int u = (t >= o) ? s[t - o] : 0;
    __syncthreads();
    s[t] += u;
    __syncthreads();
  }
  if (t < nb) bbase[t] = s[t] - v;  // exclusive
}

// ---------------- scan pass 3: in-block scan + base -> off, cursor ---------
__global__ __launch_bounds__(256) void scan_pass(const int* __restrict__ cnt,
    const int* __restrict__ bbase, int* __restrict__ off,
    int* __restrict__ cursor, int N) {
  int t = threadIdx.x;
  int i = blockIdx.x * 256 + t;
  int v = (i < N) ? cnt[i] : 0;
  int lane = t & 63;
  int incl = v;
#pragma unroll
  for (int o = 1; o < 64; o <<= 1) {
    int u = __shfl_up(incl, o, 64);
    if (lane >= o) incl += u;
  }
  __shared__ int wtot[4];
  int w = t >> 6;
  if (lane == 63) wtot[w] = incl;
  __syncthreads();
  if (t == 0) {
    int run = 0;
#pragma unroll
    for (int k = 0; k < 4; ++k) { int tmp = wtot[k]; wtot[k] = run; run += tmp; }
  }
  __syncthreads();
  int excl = incl - v + wtot[w] + bbase[blockIdx.x];
  if (i < N) { off[i] = excl; cursor[i] = excl; }
  if (i == N - 1) off[N] = excl + v;
}

// ---------------- CSR build: scatter edge ids into buckets -----------------
__global__ __launch_bounds__(256) void scatter_csr(const int* __restrict__ src,
    const int* __restrict__ dst, int* __restrict__ cursor,
    int* __restrict__ perm, int* __restrict__ src_perm, int E) {
  int e = blockIdx.x * 256 + threadIdx.x;
  if (e < E) {
    int pos = atomicAdd(&cursor[dst[e]], 1);
    perm[pos] = e;
    src_perm[pos] = src[e];
  }
}

// ---- CSR aggregation: z[n] = h[n] + sum_{e->n} relu(h[src]+ea[e]@ew+eb) ---
// Edge metadata (perm, src_perm, ea rows) is wave-uniform -> scalar loads.
// No LDS, no __syncthreads; 4-deep pipelined h-row gathers.
__global__ __launch_bounds__(128) void aggr_csr(const float* __restrict__ ea,
    const float* __restrict__ ew, const float* __restrict__ eb,
    const int* __restrict__ perm, const int* __restrict__ src_perm,
    const int* __restrict__ off, const float* __restrict__ h,
    float* __restrict__ z, int N) {
  int n = blockIdx.x;
  int j = threadIdx.x;
  int beg = off[n], end = off[n + 1];
  float wcol[16];
#pragma unroll
  for (int k = 0; k < 16; ++k) wcol[k] = ew[k * H + j];
  float bias = eb[j];
  float acc = 0.f;
  int i = beg;
  for (; i + 4 <= end; i += 4) {
    int e0 = perm[i], e1 = perm[i + 1], e2 = perm[i + 2], e3 = perm[i + 3];
    int s0 = src_perm[i], s1 = src_perm[i + 1];
    int s2 = src_perm[i + 2], s3 = src_perm[i + 3];
    // 4 independent vector gathers issued up front
    float h0 = h[(size_t)s0 * H + j];
    float h1 = h[(size_t)s1 * H + j];
    float h2 = h[(size_t)s2 * H + j];
    float h3 = h[(size_t)s3 * H + j];
    const float* a0 = ea + (size_t)e0 * 16;
    const float* a1 = ea + (size_t)e1 * 16;
    const float* a2 = ea + (size_t)e2 * 16;
    const float* a3 = ea + (size_t)e3 * 16;
    float x0 = bias, x1 = bias, x2 = bias, x3 = bias;
#pragma unroll
    for (int k = 0; k < 16; ++k) {
      x0 = fmaf(a0[k], wcol[k], x0);
      x1 = fmaf(a1[k], wcol[k], x1);
      x2 = fmaf(a2[k], wcol[k], x2);
      x3 = fmaf(a3[k], wcol[k], x3);
    }
    acc += fmaxf(x0 + h0, 0.f);
    acc += fmaxf(x1 + h1, 0.f);
    acc += fmaxf(x2 + h2, 0.f);
    acc += fmaxf(x3 + h3, 0.f);
  }
  for (; i < end; ++i) {
    int e0 = perm[i];
    int s0 = src_perm[i];
    float h0 = h[(size_t)s0 * H + j];
    const float* a0 = ea + (size_t)e0 * 16;
    float x0 = bias;
#pragma unroll
    for (int k = 0; k < 16; ++k) x0 = fmaf(a0[k], wcol[k], x0);
    acc += fmaxf(x0 + h0, 0.f);
  }
  z[(size_t)n * H + j] = h[(size_t)n * H + j] + acc;
}

// ---- GEMM1: t = z @ w1 + b1 (in-place over z), plus column sum/sumsq ------
__global__ __launch_bounds__(128) void mlp1(const float* __restrict__ zin,
    const float* __restrict__ w1, const float* __restrict__ b1,
    float* __restrict__ tout, float* __restrict__ sum,
    float* __restrict__ sumsq, int N) {
  int r0 = blockIdx.x * RB;
  int j = threadIdx.x;
  __shared__ float z[RB][H];
#pragma unroll
  for (int r = 0; r < RB; ++r) {
    int g = r0 + r;
    z[r][j] = (g < N) ? zin[(size_t)g * H + j] : 0.0f;
  }
  __syncthreads();
  float bias = b1[j];
  float acc[RB];
#pragma unroll
  for (int r = 0; r < RB; ++r) acc[r] = bias;
#pragma unroll 2
  for (int k4 = 0; k4 < H / 4; ++k4) {
    float w0 = w1[(4 * k4 + 0) * H + j];
    float wa = w1[(4 * k4 + 1) * H + j];
    float wb = w1[(4 * k4 + 2) * H + j];
    float wc = w1[(4 * k4 + 3) * H + j];
#pragma unroll
    for (int r = 0; r < RB; ++r) {
      float4 zv = *((const float4*)&z[r][4 * k4]);
      acc[r] = fmaf(zv.x, w0, acc[r]);
      acc[r] = fmaf(zv.y, wa, acc[r]);
      acc[r] = fmaf(zv.z, wb, acc[r]);
      acc[r] = fmaf(zv.w, wc, acc[r]);
    }
  }
  int nv = N - r0; if (nv > RB) nv = RB;
  float s1 = 0.f, s2 = 0.f;
#pragma unroll
  for (int r = 0; r < RB; ++r) {
    if (r < nv) {
      tout[(size_t)(r0 + r) * H + j] = acc[r];
      s1 += acc[r];
      s2 += acc[r] * acc[r];
    }
  }
  atomicAdd(&sum[j], s1);
  atomicAdd(&sumsq[j], s2);
}

// ---- BN finalize ----------------------------------------------------------
__global__ void bn_finalize(const float* __restrict__ sum,
    const float* __restrict__ sumsq, const float* __restrict__ g,
    const float* __restrict__ beta, float* __restrict__ scale,
    float* __restrict__ shift, float invN) {
  int j = threadIdx.x;
  float mu = sum[j] * invN;
  float var = sumsq[j] * invN - mu * mu;
  float inv = rsqrtf(var + 1e-5f);
  float sc = g[j] * inv;
  scale[j] = sc;
  shift[j] = beta[j] - mu * sc;
}

// ---- GEMM2: h = relu( relu(t*scale+shift) @ w2 + b2 ), optional pool ------
__global__ __launch_bounds__(128) void mlp2(const float* __restrict__ tin,
    const float* __restrict__ scale, const float* __restrict__ shift,
    const float* __restrict__ w2, const float* __restrict__ b2,
    float* __restrict__ hout, int N,
    const int* __restrict__ batch, float* __restrict__ pooled) {
  int r0 = blockIdx.x * RB;
  int j = threadIdx.x;
  __shared__ float z[RB][H];
  float sc = scale[j], sh = shift[j];
#pragma unroll
  for (int r = 0; r < RB; ++r) {
    int g = r0 + r;
    float v = (g < N) ? tin[(size_t)g * H + j] : 0.0f;
    z[r][j] = fmaxf(fmaf(v, sc, sh), 0.0f);
  }
  __syncthreads();
  float bias = b2[j];
  float acc[RB];
#pragma unroll
  for (int r = 0; r < RB; ++r) acc[r] = bias;
#pragma unroll 2
  for (int k4 = 0; k4 < H / 4; ++k4) {
    float w0 = w2[(4 * k4 + 0) * H + j];
    float wa = w2[(4 * k4 + 1) * H + j];
    float wb = w2[(4 * k4 + 2) * H + j];
    float wc = w2[(4 * k4 + 3) * H + j];
#pragma unroll
    for (int r = 0; r < RB; ++r) {
      float4 zv = *((const float4*)&z[r][4 * k4]);
      acc[r] = fmaf(zv.x, w0, acc[r]);
      acc[r] = fmaf(zv.y, wa, acc[r]);
      acc[r] = fmaf(zv.z, wb, acc[r]);
      acc[r] = fmaf(zv.w, wc, acc[r]);
    }
  }
  int nv = N - r0; if (nv > RB) nv = RB;
#pragma unroll
  for (int r = 0; r < RB; ++r) {
    if (r < nv) {
      acc[r] = fmaxf(acc[r], 0.0f);
      hout[(size_t)(r0 + r) * H + j] = acc[r];
    }
  }
  if (pooled != nullptr) {
    int curb = batch[r0];
    float pa = 0.f;
    for (int r = 0; r < nv; ++r) {
      int bb = batch[r0 + r];
      if (bb != curb) {
        atomicAdd(&pooled[(size_t)curb * H + j], pa);
        pa = 0.f;
        curb = bb;
      }
      pa += acc[r];
    }
    atomicAdd(&pooled[(size_t)curb * H + j], pa);
  }
}

// ---- final FC: out = pooled @ fc_w + fc_b ---------------------------------
__global__ __launch_bounds__(128) void fc_kernel(const float* __restrict__ pooled,
    const float* __restrict__ w, const float* __restrict__ b,
    float* __restrict__ out, int C) {
  int g = blockIdx.x;
  int j = threadIdx.x;
  __shared__ float p[H];
  p[j] = pooled[(size_t)g * H + j];
  __syncthreads();
  if (j < C) {
    float acc = b[j];
#pragma unroll 4
    for (int k = 0; k < H; ++k) acc = fmaf(p[k], w[k * C + j], acc);
    out[(size_t)g * C + j] = acc;
  }
}

extern "C" void kernel_launch(void* const* d_in, const int* in_sizes, int n_in,
                              void* d_out, int out_size, void* d_ws, size_t ws_size,
                              hipStream_t stream) {
  const float* x         = (const float*)d_in[0];
  const float* edge_attr = (const float*)d_in[1];
  const float* node_w    = (const float*)d_in[2];
  const float* node_b    = (const float*)d_in[3];
  const float* edge_w    = (const float*)d_in[4];
  const float* edge_b    = (const float*)d_in[5];
  const float* lin1_w    = (const float*)d_in[6];
  const float* lin1_b    = (const float*)d_in[7];
  const float* bn_g      = (const float*)d_in[8];
  const float* bn_b      = (const float*)d_in[9];
  const float* lin2_w    = (const float*)d_in[10];
  const float* lin2_b    = (const float*)d_in[11];
  const float* fc_w      = (const float*)d_in[12];
  const float* fc_b      = (const float*)d_in[13];
  const int*   edge_index= (const int*)d_in[14];
  const int*   batch     = (const int*)d_in[15];

  int N = in_sizes[0] / 64;       // 50000
  int E = in_sizes[1] / 16;       // 640000
  int C = in_sizes[13];           // 10
  int G = out_size / C;           // 512

  const int* src = edge_index;
  const int* dst = edge_index + E;

  float* ws     = (float*)d_ws;
  float* h      = ws;                       // [N,H]
  float* zt     = h + (size_t)N * H;        // [N,H] z and t aliased in-place
  float* pooled = zt + (size_t)N * H;       // [G,H]
  float* sums   = pooled + (size_t)G * H;   // [H]
  float* sumsq  = sums + H;                 // [H]
  float* scale  = sumsq + H;                // [H]
  float* shift  = scale + H;                // [H]
  int*   cnt      = (int*)(shift + H);      // [N]
  int*   off      = cnt + N;                // [N+1]
  int*   cursor   = off + N + 1;            // [N]
  int*   perm     = cursor + N;             // [E]
  int*   src_perm = perm + E;               // [E]
  int*   bsum     = src_perm + E;           // [nb]
  int*   bbase    = bsum + 1024;            // [nb]

  int nb = (N + 255) / 256;                 // 196 <= 1024

  // --- CSR build (every launch; deterministic) ---
  hipMemsetAsync(cnt, 0, (size_t)N * sizeof(int), stream);
  count_deg<<<(E + 255) / 256, 256, 0, stream>>>(dst, cnt, E);
  block_sum<<<nb, 256, 0, stream>>>(cnt, bsum, N);
  scan_bsum<<<1, 1024, 0, stream>>>(bsum, bbase, nb);
  scan_pass<<<nb, 256, 0, stream>>>(cnt, bbase, off, cursor, N);
  scatter_csr<<<(E + 255) / 256, 256, 0, stream>>>(src, dst, cursor, perm, src_perm, E);

  node_enc<<<N, 128, 0, stream>>>(x, node_w, node_b, h, N);

  int nblk = (N + RB - 1) / RB;
  for (int l = 0; l < 3; ++l) {
    hipMemsetAsync(sums, 0, 2 * H * sizeof(float), stream);
    aggr_csr<<<N, 128, 0, stream>>>(edge_attr, edge_w, edge_b, perm, src_perm,
                                    off, h, zt, N);
    mlp1<<<nblk, 128, 0, stream>>>(zt, lin1_w + (size_t)l * H * H,
                                   lin1_b + (size_t)l * H, zt, sums, sumsq, N);
    bn_finalize<<<1, H, 0, stream>>>(sums, sumsq, bn_g + (size_t)l * H,
                                     bn_b + (size_t)l * H, scale, shift, 1.0f / N);
    bool last = (l == 2);
    if (last) hipMemsetAsync(pooled, 0, (size_t)G * H * sizeof(float), stream);
    mlp2<<<nblk, 128, 0, stream>>>(zt, scale, shift, lin2_w + (size_t)l * H * H,
                                   lin2_b + (size_t)l * H, h, N,
                                   batch, last ? pooled : nullptr);
  }

  fc_kernel<<<G, 128, 0, stream>>>(pooled, fc_w, fc_b, (float*)d_out, C);
}

// Round 5
// 779.706 us; speedup vs baseline: 1.8470x; 1.2057x over previous
//
#include <hip/hip_runtime.h>

#define H   128
#define TM  64

// ---------------- node encoder: h = x @ node_w + node_b, x:[N,64] ----------
__global__ __launch_bounds__(128) void node_enc(const float* __restrict__ x,
    const float* __restrict__ w, const float* __restrict__ b,
    float* __restrict__ h, int N) {
  int row = blockIdx.x;
  if (row >= N) return;
  int j = threadIdx.x;
  __shared__ float xs[64];
  if (j < 64) xs[j] = x[(size_t)row * 64 + j];
  __syncthreads();
  float acc = b[j];
#pragma unroll
  for (int k = 0; k < 64; ++k) acc = fmaf(xs[k], w[k * H + j], acc);
  h[(size_t)row * H + j] = acc;
}

// ---------------- CSR build: degree count ----------------------------------
__global__ __launch_bounds__(256) void count_deg(const int* __restrict__ dst,
    int* __restrict__ cnt, int E) {
  int e = blockIdx.x * 256 + threadIdx.x;
  if (e < E) atomicAdd(&cnt[dst[e]], 1);
}

// ---------------- scan pass 1: per-block (256-elem) sums -------------------
__global__ __launch_bounds__(256) void block_sum(const int* __restrict__ cnt,
    int* __restrict__ bsum, int N) {
  int t = threadIdx.x;
  int i = blockIdx.x * 256 + t;
  int v = (i < N) ? cnt[i] : 0;
#pragma unroll
  for (int o = 32; o > 0; o >>= 1) v += __shfl_down(v, o, 64);
  __shared__ int wt[4];
  if ((t & 63) == 0) wt[t >> 6] = v;
  __syncthreads();
  if (t == 0) bsum[blockIdx.x] = wt[0] + wt[1] + wt[2] + wt[3];
}

// ---------------- scan pass 2: 1-block scan of block sums (nb <= 1024) -----
__global__ __launch_bounds__(1024) void scan_bsum(const int* __restrict__ bsum,
    int* __restrict__ bbase, int nb) {
  __shared__ int s[1024];
  int t = threadIdx.x;
  int v = (t < nb) ? bsum[t] : 0;
  s[t] = v;
  __syncthreads();
  for (int o = 1; o < 1024; o <<= 1) {
    int u = (t >= o) ? s[t - o] : 0;
    __syncthreads();
    s[t] += u;
    __syncthreads();
  }
  if (t < nb) bbase[t] = s[t] - v;  // exclusive
}

// ---------------- scan pass 3: in-block scan + base -> off, cursor ---------
__global__ __launch_bounds__(256) void scan_pass(const int* __restrict__ cnt,
    const int* __restrict__ bbase, int* __restrict__ off,
    int* __restrict__ cursor, int N) {
  int t = threadIdx.x;
  int i = blockIdx.x * 256 + t;
  int v = (i < N) ? cnt[i] : 0;
  int lane = t & 63;
  int incl = v;
#pragma unroll
  for (int o = 1; o < 64; o <<= 1) {
    int u = __shfl_up(incl, o, 64);
    if (lane >= o) incl += u;
  }
  __shared__ int wtot[4];
  int w = t >> 6;
  if (lane == 63) wtot[w] = incl;
  __syncthreads();
  if (t == 0) {
    int run = 0;
#pragma unroll
    for (int k = 0; k < 4; ++k) { int tmp = wtot[k]; wtot[k] = run; run += tmp; }
  }
  __syncthreads();
  int excl = incl - v + wtot[w] + bbase[blockIdx.x];
  if (i < N) { off[i] = excl; cursor[i] = excl; }
  if (i == N - 1) off[N] = excl + v;
}

// ---------------- CSR build: scatter edge ids into buckets -----------------
__global__ __launch_bounds__(256) void scatter_csr(const int* __restrict__ src,
    const int* __restrict__ dst, int* __restrict__ cursor,
    int* __restrict__ perm, int* __restrict__ src_perm, int E) {
  int e = blockIdx.x * 256 + threadIdx.x;
  if (e < E) {
    int pos = atomicAdd(&cursor[dst[e]], 1);
    perm[pos] = e;
    src_perm[pos] = src[e];
  }
}

// ---- CSR aggregation: z[n] = h[n] + sum_{e->n} relu(h[src]+ea[e]@ew+eb) ---
// Edge ids forced to SGPRs via readfirstlane -> ea rows become s_loads
// (SMEM pipe), freeing VMEM for the random h gathers.
__global__ __launch_bounds__(128) void aggr_csr(const float* __restrict__ ea,
    const float* __restrict__ ew, const float* __restrict__ eb,
    const int* __restrict__ perm, const int* __restrict__ src_perm,
    const int* __restrict__ off, const float* __restrict__ h,
    float* __restrict__ z, int N) {
  int n = blockIdx.x;
  int j = threadIdx.x;
  int beg = off[n], end = off[n + 1];
  float wcol[16];
#pragma unroll
  for (int k = 0; k < 16; ++k) wcol[k] = ew[k * H + j];
  float bias = eb[j];
  float acc = 0.f;
  int i = beg;
  for (; i + 4 <= end; i += 4) {
    int e0 = __builtin_amdgcn_readfirstlane(perm[i]);
    int e1 = __builtin_amdgcn_readfirstlane(perm[i + 1]);
    int e2 = __builtin_amdgcn_readfirstlane(perm[i + 2]);
    int e3 = __builtin_amdgcn_readfirstlane(perm[i + 3]);
    int s0 = __builtin_amdgcn_readfirstlane(src_perm[i]);
    int s1 = __builtin_amdgcn_readfirstlane(src_perm[i + 1]);
    int s2 = __builtin_amdgcn_readfirstlane(src_perm[i + 2]);
    int s3 = __builtin_amdgcn_readfirstlane(src_perm[i + 3]);
    float h0 = h[(size_t)s0 * H + j];
    float h1 = h[(size_t)s1 * H + j];
    float h2 = h[(size_t)s2 * H + j];
    float h3 = h[(size_t)s3 * H + j];
    const float* a0 = ea + (size_t)e0 * 16;
    const float* a1 = ea + (size_t)e1 * 16;
    const float* a2 = ea + (size_t)e2 * 16;
    const float* a3 = ea + (size_t)e3 * 16;
    float x0 = bias, x1 = bias, x2 = bias, x3 = bias;
#pragma unroll
    for (int k = 0; k < 16; ++k) {
      x0 = fmaf(a0[k], wcol[k], x0);
      x1 = fmaf(a1[k], wcol[k], x1);
      x2 = fmaf(a2[k], wcol[k], x2);
      x3 = fmaf(a3[k], wcol[k], x3);
    }
    acc += fmaxf(x0 + h0, 0.f);
    acc += fmaxf(x1 + h1, 0.f);
    acc += fmaxf(x2 + h2, 0.f);
    acc += fmaxf(x3 + h3, 0.f);
  }
  for (; i < end; ++i) {
    int e0 = __builtin_amdgcn_readfirstlane(perm[i]);
    int s0 = __builtin_amdgcn_readfirstlane(src_perm[i]);
    float h0 = h[(size_t)s0 * H + j];
    const float* a0 = ea + (size_t)e0 * 16;
    float x0 = bias;
#pragma unroll
    for (int k = 0; k < 16; ++k) x0 = fmaf(a0[k], wcol[k], x0);
    acc += fmaxf(x0 + h0, 0.f);
  }
  z[(size_t)n * H + j] = h[(size_t)n * H + j] + acc;
}

// ---- GEMM1: t = z @ w1 + b1, 64x128 tile, 8r x 4c per thread --------------
__global__ __launch_bounds__(256) void mlp1(const float* __restrict__ zin,
    const float* __restrict__ w1, const float* __restrict__ b1,
    float* __restrict__ tout, float* __restrict__ sum,
    float* __restrict__ sumsq, int N) {
  int r0 = blockIdx.x * TM;
  int tid = threadIdx.x;
  int cl = tid & 31;      // column lane: cols cl*4 .. cl*4+3
  int rg = tid >> 5;      // row group: rows rg*8 .. rg*8+7
  int c0 = cl * 4;
  __shared__ float z[TM][H];
  const float4* zin4 = (const float4*)zin;
#pragma unroll
  for (int f = 0; f < 8; ++f) {
    int q = f * 256 + tid;
    int row = q >> 5, col4 = q & 31;
    int g = r0 + row;
    float4 v = make_float4(0.f, 0.f, 0.f, 0.f);
    if (g < N) v = zin4[(size_t)g * 32 + col4];
    *(float4*)&z[row][col4 * 4] = v;
  }
  __syncthreads();
  float4 bv = *(const float4*)&b1[c0];
  float acc[8][4];
#pragma unroll
  for (int r = 0; r < 8; ++r) {
    acc[r][0] = bv.x; acc[r][1] = bv.y; acc[r][2] = bv.z; acc[r][3] = bv.w;
  }
  int zr = rg * 8;
#pragma unroll 4
  for (int k4 = 0; k4 < 32; ++k4) {
    float4 wa = *(const float4*)&w1[(k4 * 4 + 0) * H + c0];
    float4 wb = *(const float4*)&w1[(k4 * 4 + 1) * H + c0];
    float4 wc = *(const float4*)&w1[(k4 * 4 + 2) * H + c0];
    float4 wd = *(const float4*)&w1[(k4 * 4 + 3) * H + c0];
#pragma unroll
    for (int r = 0; r < 8; ++r) {
      float4 zv = *(const float4*)&z[zr + r][k4 * 4];
      acc[r][0] = fmaf(zv.x, wa.x, acc[r][0]);
      acc[r][1] = fmaf(zv.x, wa.y, acc[r][1]);
      acc[r][2] = fmaf(zv.x, wa.z, acc[r][2]);
      acc[r][3] = fmaf(zv.x, wa.w, acc[r][3]);
      acc[r][0] = fmaf(zv.y, wb.x, acc[r][0]);
      acc[r][1] = fmaf(zv.y, wb.y, acc[r][1]);
      acc[r][2] = fmaf(zv.y, wb.z, acc[r][2]);
      acc[r][3] = fmaf(zv.y, wb.w, acc[r][3]);
      acc[r][0] = fmaf(zv.z, wc.x, acc[r][0]);
      acc[r][1] = fmaf(zv.z, wc.y, acc[r][1]);
      acc[r][2] = fmaf(zv.z, wc.z, acc[r][2]);
      acc[r][3] = fmaf(zv.z, wc.w, acc[r][3]);
      acc[r][0] = fmaf(zv.w, wd.x, acc[r][0]);
      acc[r][1] = fmaf(zv.w, wd.y, acc[r][1]);
      acc[r][2] = fmaf(zv.w, wd.z, acc[r][2]);
      acc[r][3] = fmaf(zv.w, wd.w, acc[r][3]);
    }
  }
  float s1[4] = {0.f, 0.f, 0.f, 0.f}, s2[4] = {0.f, 0.f, 0.f, 0.f};
#pragma unroll
  for (int r = 0; r < 8; ++r) {
    int g = r0 + zr + r;
    if (g < N) {
      *(float4*)&tout[(size_t)g * H + c0] =
          make_float4(acc[r][0], acc[r][1], acc[r][2], acc[r][3]);
#pragma unroll
      for (int c = 0; c < 4; ++c) {
        s1[c] += acc[r][c];
        s2[c] += acc[r][c] * acc[r][c];
      }
    }
  }
  // block-level reduction of BN partials before atomics
  __syncthreads();
  float* red = &z[0][0];  // reuse: [0..1023]=s1, [1024..2047]=s2
#pragma unroll
  for (int c = 0; c < 4; ++c) {
    red[rg * H + c0 + c] = s1[c];
    red[1024 + rg * H + c0 + c] = s2[c];
  }
  __syncthreads();
  if (tid < H) {
    float a = 0.f, b = 0.f;
#pragma unroll
    for (int g = 0; g < 8; ++g) {
      a += red[g * H + tid];
      b += red[1024 + g * H + tid];
    }
    atomicAdd(&sum[tid], a);
    atomicAdd(&sumsq[tid], b);
  }
}

// ---- BN finalize ----------------------------------------------------------
__global__ void bn_finalize(const float* __restrict__ sum,
    const float* __restrict__ sumsq, const float* __restrict__ g,
    const float* __restrict__ beta, float* __restrict__ scale,
    float* __restrict__ shift, float invN) {
  int j = threadIdx.x;
  float mu = sum[j] * invN;
  float var = sumsq[j] * invN - mu * mu;
  float inv = rsqrtf(var + 1e-5f);
  float sc = g[j] * inv;
  scale[j] = sc;
  shift[j] = beta[j] - mu * sc;
}

// ---- GEMM2: h = relu( relu(t*sc+sh) @ w2 + b2 ), fused pool on last layer -
__global__ __launch_bounds__(256) void mlp2(const float* __restrict__ tin,
    const float* __restrict__ scale, const float* __restrict__ shift,
    const float* __restrict__ w2, const float* __restrict__ b2,
    float* __restrict__ hout, int N,
    const int* __restrict__ batch, float* __restrict__ pooled) {
  int r0 = blockIdx.x * TM;
  int tid = threadIdx.x;
  int cl = tid & 31;
  int rg = tid >> 5;
  int c0 = cl * 4;
  __shared__ float z[TM][H];
  const float4* tin4 = (const float4*)tin;
#pragma unroll
  for (int f = 0; f < 8; ++f) {
    int q = f * 256 + tid;
    int row = q >> 5, col4 = q & 31;
    int g = r0 + row;
    float4 v = make_float4(0.f, 0.f, 0.f, 0.f);
    if (g < N) {
      v = tin4[(size_t)g * 32 + col4];
      float4 sc = *(const float4*)&scale[col4 * 4];
      float4 sh = *(const float4*)&shift[col4 * 4];
      v.x = fmaxf(fmaf(v.x, sc.x, sh.x), 0.f);
      v.y = fmaxf(fmaf(v.y, sc.y, sh.y), 0.f);
      v.z = fmaxf(fmaf(v.z, sc.z, sh.z), 0.f);
      v.w = fmaxf(fmaf(v.w, sc.w, sh.w), 0.f);
    }
    *(float4*)&z[row][col4 * 4] = v;
  }
  __syncthreads();
  float4 bv = *(const float4*)&b2[c0];
  float acc[8][4];
#pragma unroll
  for (int r = 0; r < 8; ++r) {
    acc[r][0] = bv.x; acc[r][1] = bv.y; acc[r][2] = bv.z; acc[r][3] = bv.w;
  }
  int zr = rg * 8;
#pragma unroll 4
  for (int k4 = 0; k4 < 32; ++k4) {
    float4 wa = *(const float4*)&w2[(k4 * 4 + 0) * H + c0];
    float4 wb = *(const float4*)&w2[(k4 * 4 + 1) * H + c0];
    float4 wc = *(const float4*)&w2[(k4 * 4 + 2) * H + c0];
    float4 wd = *(const float4*)&w2[(k4 * 4 + 3) * H + c0];
#pragma unroll
    for (int r = 0; r < 8; ++r) {
      float4 zv = *(const float4*)&z[zr + r][k4 * 4];
      acc[r][0] = fmaf(zv.x, wa.x, acc[r][0]);
      acc[r][1] = fmaf(zv.x, wa.y, acc[r][1]);
      acc[r][2] = fmaf(zv.x, wa.z, acc[r][2]);
      acc[r][3] = fmaf(zv.x, wa.w, acc[r][3]);
      acc[r][0] = fmaf(zv.y, wb.x, acc[r][0]);
      acc[r][1] = fmaf(zv.y, wb.y, acc[r][1]);
      acc[r][2] = fmaf(zv.y, wb.z, acc[r][2]);
      acc[r][3] = fmaf(zv.y, wb.w, acc[r][3]);
      acc[r][0] = fmaf(zv.z, wc.x, acc[r][0]);
      acc[r][1] = fmaf(zv.z, wc.y, acc[r][1]);
      acc[r][2] = fmaf(zv.z, wc.z, acc[r][2]);
      acc[r][3] = fmaf(zv.z, wc.w, acc[r][3]);
      acc[r][0] = fmaf(zv.w, wd.x, acc[r][0]);
      acc[r][1] = fmaf(zv.w, wd.y, acc[r][1]);
      acc[r][2] = fmaf(zv.w, wd.z, acc[r][2]);
      acc[r][3] = fmaf(zv.w, wd.w, acc[r][3]);
    }
  }
#pragma unroll
  for (int r = 0; r < 8; ++r) {
    int g = r0 + zr + r;
    if (g < N) {
      acc[r][0] = fmaxf(acc[r][0], 0.f);
      acc[r][1] = fmaxf(acc[r][1], 0.f);
      acc[r][2] = fmaxf(acc[r][2], 0.f);
      acc[r][3] = fmaxf(acc[r][3], 0.f);
      *(float4*)&hout[(size_t)g * H + c0] =
          make_float4(acc[r][0], acc[r][1], acc[r][2], acc[r][3]);
    }
  }
  if (pooled != nullptr) {
    int gbase = r0 + zr;
    if (gbase < N) {
      int cur = batch[gbase];
      float pa[4] = {0.f, 0.f, 0.f, 0.f};
      for (int r = 0; r < 8; ++r) {
        int g = gbase + r;
        if (g >= N) break;
        int bb = batch[g];
        if (bb != cur) {
#pragma unroll
          for (int c = 0; c < 4; ++c)
            atomicAdd(&pooled[(size_t)cur * H + c0 + c], pa[c]);
          pa[0] = pa[1] = pa[2] = pa[3] = 0.f;
          cur = bb;
        }
#pragma unroll
        for (int c = 0; c < 4; ++c) pa[c] += acc[r][c];
      }
#pragma unroll
      for (int c = 0; c < 4; ++c)
        atomicAdd(&pooled[(size_t)cur * H + c0 + c], pa[c]);
    }
  }
}

// ---- final FC: out = pooled @ fc_w + fc_b ---------------------------------
__global__ __launch_bounds__(128) void fc_kernel(const float* __restrict__ pooled,
    const float* __restrict__ w, const float* __restrict__ b,
    float* __restrict__ out, int C) {
  int g = blockIdx.x;
  int j = threadIdx.x;
  __shared__ float p[H];
  p[j] = pooled[(size_t)g * H + j];
  __syncthreads();
  if (j < C) {
    float acc = b[j];
#pragma unroll 4
    for (int k = 0; k < H; ++k) acc = fmaf(p[k], w[k * C + j], acc);
    out[(size_t)g * C + j] = acc;
  }
}

extern "C" void kernel_launch(void* const* d_in, const int* in_sizes, int n_in,
                              void* d_out, int out_size, void* d_ws, size_t ws_size,
                              hipStream_t stream) {
  const float* x         = (const float*)d_in[0];
  const float* edge_attr = (const float*)d_in[1];
  const float* node_w    = (const float*)d_in[2];
  const float* node_b    = (const float*)d_in[3];
  const float* edge_w    = (const float*)d_in[4];
  const float* edge_b    = (const float*)d_in[5];
  const float* lin1_w    = (const float*)d_in[6];
  const float* lin1_b    = (const float*)d_in[7];
  const float* bn_g      = (const float*)d_in[8];
  const float* bn_b      = (const float*)d_in[9];
  const float* lin2_w    = (const float*)d_in[10];
  const float* lin2_b    = (const float*)d_in[11];
  const float* fc_w      = (const float*)d_in[12];
  const float* fc_b      = (const float*)d_in[13];
  const int*   edge_index= (const int*)d_in[14];
  const int*   batch     = (const int*)d_in[15];

  int N = in_sizes[0] / 64;       // 50000
  int E = in_sizes[1] / 16;       // 640000
  int C = in_sizes[13];           // 10
  int G = out_size / C;           // 512

  const int* src = edge_index;
  const int* dst = edge_index + E;

  float* ws     = (float*)d_ws;
  float* h      = ws;                       // [N,H]
  float* zt     = h + (size_t)N * H;        // [N,H] z and t aliased in-place
  float* pooled = zt + (size_t)N * H;       // [G,H]
  float* sums   = pooled + (size_t)G * H;   // [H]
  float* sumsq  = sums + H;                 // [H]
  float* scale  = sumsq + H;                // [H]
  float* shift  = scale + H;                // [H]
  int*   cnt      = (int*)(shift + H);      // [N]
  int*   off      = cnt + N;                // [N+1]
  int*   cursor   = off + N + 1;            // [N]
  int*   perm     = cursor + N;             // [E]
  int*   src_perm = perm + E;               // [E]
  int*   bsum     = src_perm + E;           // [nb]
  int*   bbase    = bsum + 1024;            // [nb]

  int nb = (N + 255) / 256;                 // 196 <= 1024

  // --- CSR build (every launch; deterministic) ---
  hipMemsetAsync(cnt, 0, (size_t)N * sizeof(int), stream);
  count_deg<<<(E + 255) / 256, 256, 0, stream>>>(dst, cnt, E);
  block_sum<<<nb, 256, 0, stream>>>(cnt, bsum, N);
  scan_bsum<<<1, 1024, 0, stream>>>(bsum, bbase, nb);
  scan_pass<<<nb, 256, 0, stream>>>(cnt, bbase, off, cursor, N);
  scatter_csr<<<(E + 255) / 256, 256, 0, stream>>>(src, dst, cursor, perm, src_perm, E);

  node_enc<<<N, 128, 0, stream>>>(x, node_w, node_b, h, N);

  int mblk = (N + TM - 1) / TM;
  for (int l = 0; l < 3; ++l) {
    hipMemsetAsync(sums, 0, 2 * H * sizeof(float), stream);
    aggr_csr<<<N, 128, 0, stream>>>(edge_attr, edge_w, edge_b, perm, src_perm,
                                    off, h, zt, N);
    mlp1<<<mblk, 256, 0, stream>>>(zt, lin1_w + (size_t)l * H * H,
                                   lin1_b + (size_t)l * H, zt, sums, sumsq, N);
    bn_finalize<<<1, H, 0, stream>>>(sums, sumsq, bn_g + (size_t)l * H,
                                     bn_b + (size_t)l * H, scale, shift, 1.0f / N);
    bool last = (l == 2);
    if (last) hipMemsetAsync(pooled, 0, (size_t)G * H * sizeof(float), stream);
    mlp2<<<mblk, 256, 0, stream>>>(zt, scale, shift, lin2_w + (size_t)l * H * H,
                                   lin2_b + (size_t)l * H, h, N,
                                   batch, last ? pooled : nullptr);
  }

  fc_kernel<<<G, 128, 0, stream>>>(pooled, fc_w, fc_b, (float*)d_out, C);
}

// Round 6
// 764.279 us; speedup vs baseline: 1.8843x; 1.0202x over previous
//
#include <hip/hip_runtime.h>

#define H   128
#define TM  64

// ---------------- node encoder: h = x @ node_w + node_b, x:[N,64] ----------
__global__ __launch_bounds__(128) void node_enc(const float* __restrict__ x,
    const float* __restrict__ w, const float* __restrict__ b,
    float* __restrict__ h, int N) {
  int row = blockIdx.x;
  if (row >= N) return;
  int j = threadIdx.x;
  __shared__ float xs[64];
  if (j < 64) xs[j] = x[(size_t)row * 64 + j];
  __syncthreads();
  float acc = b[j];
#pragma unroll
  for (int k = 0; k < 64; ++k) acc = fmaf(xs[k], w[k * H + j], acc);
  h[(size_t)row * H + j] = acc;
}

// ---------------- CSR build: degree count ----------------------------------
__global__ __launch_bounds__(256) void count_deg(const int* __restrict__ dst,
    int* __restrict__ cnt, int E) {
  int e = blockIdx.x * 256 + threadIdx.x;
  if (e < E) atomicAdd(&cnt[dst[e]], 1);
}

// ---------------- scan pass 1: per-block (256-elem) sums -------------------
__global__ __launch_bounds__(256) void block_sum(const int* __restrict__ cnt,
    int* __restrict__ bsum, int N) {
  int t = threadIdx.x;
  int i = blockIdx.x * 256 + t;
  int v = (i < N) ? cnt[i] : 0;
#pragma unroll
  for (int o = 32; o > 0; o >>= 1) v += __shfl_down(v, o, 64);
  __shared__ int wt[4];
  if ((t & 63) == 0) wt[t >> 6] = v;
  __syncthreads();
  if (t == 0) bsum[blockIdx.x] = wt[0] + wt[1] + wt[2] + wt[3];
}

// ---------------- scan pass 2: 1-block scan of block sums (nb <= 1024) -----
__global__ __launch_bounds__(1024) void scan_bsum(const int* __restrict__ bsum,
    int* __restrict__ bbase, int nb) {
  __shared__ int s[1024];
  int t = threadIdx.x;
  int v = (t < nb) ? bsum[t] : 0;
  s[t] = v;
  __syncthreads();
  for (int o = 1; o < 1024; o <<= 1) {
    int u = (t >= o) ? s[t - o] : 0;
    __syncthreads();
    s[t] += u;
    __syncthreads();
  }
  if (t < nb) bbase[t] = s[t] - v;  // exclusive
}

// ---------------- scan pass 3: in-block scan + base -> off, cursor ---------
__global__ __launch_bounds__(256) void scan_pass(const int* __restrict__ cnt,
    const int* __restrict__ bbase, int* __restrict__ off,
    int* __restrict__ cursor, int N) {
  int t = threadIdx.x;
  int i = blockIdx.x * 256 + t;
  int v = (i < N) ? cnt[i] : 0;
  int lane = t & 63;
  int incl = v;
#pragma unroll
  for (int o = 1; o < 64; o <<= 1) {
    int u = __shfl_up(incl, o, 64);
    if (lane >= o) incl += u;
  }
  __shared__ int wtot[4];
  int w = t >> 6;
  if (lane == 63) wtot[w] = incl;
  __syncthreads();
  if (t == 0) {
    int run = 0;
#pragma unroll
    for (int k = 0; k < 4; ++k) { int tmp = wtot[k]; wtot[k] = run; run += tmp; }
  }
  __syncthreads();
  int excl = incl - v + wtot[w] + bbase[blockIdx.x];
  if (i < N) { off[i] = excl; cursor[i] = excl; }
  if (i == N - 1) off[N] = excl + v;
}

// ---------------- CSR build: scatter edge ids into buckets -----------------
__global__ __launch_bounds__(256) void scatter_csr(const int* __restrict__ src,
    const int* __restrict__ dst, int* __restrict__ cursor,
    int* __restrict__ perm, int* __restrict__ src_perm, int E) {
  int e = blockIdx.x * 256 + threadIdx.x;
  if (e < E) {
    int pos = atomicAdd(&cursor[dst[e]], 1);
    perm[pos] = e;
    src_perm[pos] = src[e];
  }
}

// ---- CSR aggregation: z[n] = h[n] + sum_{e->n} relu(h[src]+ea[e]@ew+eb) ---
// Wave-per-node: 256-thread block = 4 waves = 4 nodes. Each lane owns 2
// columns (float2). Per edge: ONE s_load chain (perm -> ea row dwordx16),
// ONE global_load_dwordx2 for the h row. 2-edge unroll keeps 2 gather
// chains in flight. No LDS, no barriers.
__global__ __launch_bounds__(256) void aggr_csr(const float* __restrict__ ea,
    const float* __restrict__ ew, const float* __restrict__ eb,
    const int* __restrict__ perm, const int* __restrict__ src_perm,
    const int* __restrict__ off, const float* __restrict__ h,
    float* __restrict__ z, int N) {
  int wid = threadIdx.x >> 6;
  int lane = threadIdx.x & 63;
  int n = blockIdx.x * 4 + wid;
  if (n >= N) return;
  int beg = off[n], end = off[n + 1];
  int c = lane * 2;
  float2 wc[16];
#pragma unroll
  for (int k = 0; k < 16; ++k) wc[k] = *(const float2*)&ew[k * H + c];
  float2 bias = *(const float2*)&eb[c];
  float ax = 0.f, ay = 0.f;
  int i = beg;
  for (; i + 2 <= end; i += 2) {
    int e0 = __builtin_amdgcn_readfirstlane(perm[i]);
    int e1 = __builtin_amdgcn_readfirstlane(perm[i + 1]);
    int s0 = __builtin_amdgcn_readfirstlane(src_perm[i]);
    int s1 = __builtin_amdgcn_readfirstlane(src_perm[i + 1]);
    float2 h0 = *(const float2*)&h[(size_t)s0 * H + c];
    float2 h1 = *(const float2*)&h[(size_t)s1 * H + c];
    const float* a0 = ea + (size_t)e0 * 16;
    const float* a1 = ea + (size_t)e1 * 16;
    float x0 = bias.x, y0 = bias.y, x1 = bias.x, y1 = bias.y;
#pragma unroll
    for (int k = 0; k < 16; ++k) {
      float a0k = a0[k], a1k = a1[k];
      x0 = fmaf(a0k, wc[k].x, x0);
      y0 = fmaf(a0k, wc[k].y, y0);
      x1 = fmaf(a1k, wc[k].x, x1);
      y1 = fmaf(a1k, wc[k].y, y1);
    }
    ax += fmaxf(x0 + h0.x, 0.f) + fmaxf(x1 + h1.x, 0.f);
    ay += fmaxf(y0 + h0.y, 0.f) + fmaxf(y1 + h1.y, 0.f);
  }
  if (i < end) {
    int e0 = __builtin_amdgcn_readfirstlane(perm[i]);
    int s0 = __builtin_amdgcn_readfirstlane(src_perm[i]);
    float2 h0 = *(const float2*)&h[(size_t)s0 * H + c];
    const float* a0 = ea + (size_t)e0 * 16;
    float x0 = bias.x, y0 = bias.y;
#pragma unroll
    for (int k = 0; k < 16; ++k) {
      float a0k = a0[k];
      x0 = fmaf(a0k, wc[k].x, x0);
      y0 = fmaf(a0k, wc[k].y, y0);
    }
    ax += fmaxf(x0 + h0.x, 0.f);
    ay += fmaxf(y0 + h0.y, 0.f);
  }
  float2 hn = *(const float2*)&h[(size_t)n * H + c];
  *(float2*)&z[(size_t)n * H + c] = make_float2(hn.x + ax, hn.y + ay);
}

// ---- GEMM1: t = z @ w1 + b1, 64x128 tile, 8r x 4c per thread --------------
__global__ __launch_bounds__(256) void mlp1(const float* __restrict__ zin,
    const float* __restrict__ w1, const float* __restrict__ b1,
    float* __restrict__ tout, float* __restrict__ sum,
    float* __restrict__ sumsq, int N) {
  int r0 = blockIdx.x * TM;
  int tid = threadIdx.x;
  int cl = tid & 31;      // column lane: cols cl*4 .. cl*4+3
  int rg = tid >> 5;      // row group: rows rg*8 .. rg*8+7
  int c0 = cl * 4;
  __shared__ float z[TM][H];
  const float4* zin4 = (const float4*)zin;
#pragma unroll
  for (int f = 0; f < 8; ++f) {
    int q = f * 256 + tid;
    int row = q >> 5, col4 = q & 31;
    int g = r0 + row;
    float4 v = make_float4(0.f, 0.f, 0.f, 0.f);
    if (g < N) v = zin4[(size_t)g * 32 + col4];
    *(float4*)&z[row][col4 * 4] = v;
  }
  __syncthreads();
  float4 bv = *(const float4*)&b1[c0];
  float acc[8][4];
#pragma unroll
  for (int r = 0; r < 8; ++r) {
    acc[r][0] = bv.x; acc[r][1] = bv.y; acc[r][2] = bv.z; acc[r][3] = bv.w;
  }
  int zr = rg * 8;
#pragma unroll 4
  for (int k4 = 0; k4 < 32; ++k4) {
    float4 wa = *(const float4*)&w1[(k4 * 4 + 0) * H + c0];
    float4 wb = *(const float4*)&w1[(k4 * 4 + 1) * H + c0];
    float4 wc = *(const float4*)&w1[(k4 * 4 + 2) * H + c0];
    float4 wd = *(const float4*)&w1[(k4 * 4 + 3) * H + c0];
#pragma unroll
    for (int r = 0; r < 8; ++r) {
      float4 zv = *(const float4*)&z[zr + r][k4 * 4];
      acc[r][0] = fmaf(zv.x, wa.x, acc[r][0]);
      acc[r][1] = fmaf(zv.x, wa.y, acc[r][1]);
      acc[r][2] = fmaf(zv.x, wa.z, acc[r][2]);
      acc[r][3] = fmaf(zv.x, wa.w, acc[r][3]);
      acc[r][0] = fmaf(zv.y, wb.x, acc[r][0]);
      acc[r][1] = fmaf(zv.y, wb.y, acc[r][1]);
      acc[r][2] = fmaf(zv.y, wb.z, acc[r][2]);
      acc[r][3] = fmaf(zv.y, wb.w, acc[r][3]);
      acc[r][0] = fmaf(zv.z, wc.x, acc[r][0]);
      acc[r][1] = fmaf(zv.z, wc.y, acc[r][1]);
      acc[r][2] = fmaf(zv.z, wc.z, acc[r][2]);
      acc[r][3] = fmaf(zv.z, wc.w, acc[r][3]);
      acc[r][0] = fmaf(zv.w, wd.x, acc[r][0]);
      acc[r][1] = fmaf(zv.w, wd.y, acc[r][1]);
      acc[r][2] = fmaf(zv.w, wd.z, acc[r][2]);
      acc[r][3] = fmaf(zv.w, wd.w, acc[r][3]);
    }
  }
  float s1[4] = {0.f, 0.f, 0.f, 0.f}, s2[4] = {0.f, 0.f, 0.f, 0.f};
#pragma unroll
  for (int r = 0; r < 8; ++r) {
    int g = r0 + zr + r;
    if (g < N) {
      *(float4*)&tout[(size_t)g * H + c0] =
          make_float4(acc[r][0], acc[r][1], acc[r][2], acc[r][3]);
#pragma unroll
      for (int c = 0; c < 4; ++c) {
        s1[c] += acc[r][c];
        s2[c] += acc[r][c] * acc[r][c];
      }
    }
  }
  // block-level reduction of BN partials before atomics
  __syncthreads();
  float* red = &z[0][0];  // reuse: [0..1023]=s1, [1024..2047]=s2
#pragma unroll
  for (int c = 0; c < 4; ++c) {
    red[rg * H + c0 + c] = s1[c];
    red[1024 + rg * H + c0 + c] = s2[c];
  }
  __syncthreads();
  if (tid < H) {
    float a = 0.f, b = 0.f;
#pragma unroll
    for (int g = 0; g < 8; ++g) {
      a += red[g * H + tid];
      b += red[1024 + g * H + tid];
    }
    atomicAdd(&sum[tid], a);
    atomicAdd(&sumsq[tid], b);
  }
}

// ---- BN finalize ----------------------------------------------------------
__global__ void bn_finalize(const float* __restrict__ sum,
    const float* __restrict__ sumsq, const float* __restrict__ g,
    const float* __restrict__ beta, float* __restrict__ scale,
    float* __restrict__ shift, float invN) {
  int j = threadIdx.x;
  float mu = sum[j] * invN;
  float var = sumsq[j] * invN - mu * mu;
  float inv = rsqrtf(var + 1e-5f);
  float sc = g[j] * inv;
  scale[j] = sc;
  shift[j] = beta[j] - mu * sc;
}

// ---- GEMM2: h = relu( relu(t*sc+sh) @ w2 + b2 ), fused pool on last layer -
__global__ __launch_bounds__(256) void mlp2(const float* __restrict__ tin,
    const float* __restrict__ scale, const float* __restrict__ shift,
    const float* __restrict__ w2, const float* __restrict__ b2,
    float* __restrict__ hout, int N,
    const int* __restrict__ batch, float* __restrict__ pooled) {
  int r0 = blockIdx.x * TM;
  int tid = threadIdx.x;
  int cl = tid & 31;
  int rg = tid >> 5;
  int c0 = cl * 4;
  __shared__ float z[TM][H];
  const float4* tin4 = (const float4*)tin;
#pragma unroll
  for (int f = 0; f < 8; ++f) {
    int q = f * 256 + tid;
    int row = q >> 5, col4 = q & 31;
    int g = r0 + row;
    float4 v = make_float4(0.f, 0.f, 0.f, 0.f);
    if (g < N) {
      v = tin4[(size_t)g * 32 + col4];
      float4 sc = *(const float4*)&scale[col4 * 4];
      float4 sh = *(const float4*)&shift[col4 * 4];
      v.x = fmaxf(fmaf(v.x, sc.x, sh.x), 0.f);
      v.y = fmaxf(fmaf(v.y, sc.y, sh.y), 0.f);
      v.z = fmaxf(fmaf(v.z, sc.z, sh.z), 0.f);
      v.w = fmaxf(fmaf(v.w, sc.w, sh.w), 0.f);
    }
    *(float4*)&z[row][col4 * 4] = v;
  }
  __syncthreads();
  float4 bv = *(const float4*)&b2[c0];
  float acc[8][4];
#pragma unroll
  for (int r = 0; r < 8; ++r) {
    acc[r][0] = bv.x; acc[r][1] = bv.y; acc[r][2] = bv.z; acc[r][3] = bv.w;
  }
  int zr = rg * 8;
#pragma unroll 4
  for (int k4 = 0; k4 < 32; ++k4) {
    float4 wa = *(const float4*)&w2[(k4 * 4 + 0) * H + c0];
    float4 wb = *(const float4*)&w2[(k4 * 4 + 1) * H + c0];
    float4 wc = *(const float4*)&w2[(k4 * 4 + 2) * H + c0];
    float4 wd = *(const float4*)&w2[(k4 * 4 + 3) * H + c0];
#pragma unroll
    for (int r = 0; r < 8; ++r) {
      float4 zv = *(const float4*)&z[zr + r][k4 * 4];
      acc[r][0] = fmaf(zv.x, wa.x, acc[r][0]);
      acc[r][1] = fmaf(zv.x, wa.y, acc[r][1]);
      acc[r][2] = fmaf(zv.x, wa.z, acc[r][2]);
      acc[r][3] = fmaf(zv.x, wa.w, acc[r][3]);
      acc[r][0] = fmaf(zv.y, wb.x, acc[r][0]);
      acc[r][1] = fmaf(zv.y, wb.y, acc[r][1]);
      acc[r][2] = fmaf(zv.y, wb.z, acc[r][2]);
      acc[r][3] = fmaf(zv.y, wb.w, acc[r][3]);
      acc[r][0] = fmaf(zv.z, wc.x, acc[r][0]);
      acc[r][1] = fmaf(zv.z, wc.y, acc[r][1]);
      acc[r][2] = fmaf(zv.z, wc.z, acc[r][2]);
      acc[r][3] = fmaf(zv.z, wc.w, acc[r][3]);
      acc[r][0] = fmaf(zv.w, wd.x, acc[r][0]);
      acc[r][1] = fmaf(zv.w, wd.y, acc[r][1]);
      acc[r][2] = fmaf(zv.w, wd.z, acc[r][2]);
      acc[r][3] = fmaf(zv.w, wd.w, acc[r][3]);
    }
  }
#pragma unroll
  for (int r = 0; r < 8; ++r) {
    int g = r0 + zr + r;
    if (g < N) {
      acc[r][0] = fmaxf(acc[r][0], 0.f);
      acc[r][1] = fmaxf(acc[r][1], 0.f);
      acc[r][2] = fmaxf(acc[r][2], 0.f);
      acc[r][3] = fmaxf(acc[r][3], 0.f);
      *(float4*)&hout[(size_t)g * H + c0] =
          make_float4(acc[r][0], acc[r][1], acc[r][2], acc[r][3]);
    }
  }
  if (pooled != nullptr) {
    int gbase = r0 + zr;
    if (gbase < N) {
      int cur = batch[gbase];
      float pa[4] = {0.f, 0.f, 0.f, 0.f};
      for (int r = 0; r < 8; ++r) {
        int g = gbase + r;
        if (g >= N) break;
        int bb = batch[g];
        if (bb != cur) {
#pragma unroll
          for (int c = 0; c < 4; ++c)
            atomicAdd(&pooled[(size_t)cur * H + c0 + c], pa[c]);
          pa[0] = pa[1] = pa[2] = pa[3] = 0.f;
          cur = bb;
        }
#pragma unroll
        for (int c = 0; c < 4; ++c) pa[c] += acc[r][c];
      }
#pragma unroll
      for (int c = 0; c < 4; ++c)
        atomicAdd(&pooled[(size_t)cur * H + c0 + c], pa[c]);
    }
  }
}

// ---- final FC: out = pooled @ fc_w + fc_b ---------------------------------
__global__ __launch_bounds__(128) void fc_kernel(const float* __restrict__ pooled,
    const float* __restrict__ w, const float* __restrict__ b,
    float* __restrict__ out, int C) {
  int g = blockIdx.x;
  int j = threadIdx.x;
  __shared__ float p[H];
  p[j] = pooled[(size_t)g * H + j];
  __syncthreads();
  if (j < C) {
    float acc = b[j];
#pragma unroll 4
    for (int k = 0; k < H; ++k) acc = fmaf(p[k], w[k * C + j], acc);
    out[(size_t)g * C + j] = acc;
  }
}

extern "C" void kernel_launch(void* const* d_in, const int* in_sizes, int n_in,
                              void* d_out, int out_size, void* d_ws, size_t ws_size,
                              hipStream_t stream) {
  const float* x         = (const float*)d_in[0];
  const float* edge_attr = (const float*)d_in[1];
  const float* node_w    = (const float*)d_in[2];
  const float* node_b    = (const float*)d_in[3];
  const float* edge_w    = (const float*)d_in[4];
  const float* edge_b    = (const float*)d_in[5];
  const float* lin1_w    = (const float*)d_in[6];
  const float* lin1_b    = (const float*)d_in[7];
  const float* bn_g      = (const float*)d_in[8];
  const float* bn_b      = (const float*)d_in[9];
  const float* lin2_w    = (const float*)d_in[10];
  const float* lin2_b    = (const float*)d_in[11];
  const float* fc_w      = (const float*)d_in[12];
  const float* fc_b      = (const float*)d_in[13];
  const int*   edge_index= (const int*)d_in[14];
  const int*   batch     = (const int*)d_in[15];

  int N = in_sizes[0] / 64;       // 50000
  int E = in_sizes[1] / 16;       // 640000
  int C = in_sizes[13];           // 10
  int G = out_size / C;           // 512

  const int* src = edge_index;
  const int* dst = edge_index + E;

  float* ws     = (float*)d_ws;
  float* h      = ws;                       // [N,H]
  float* zt     = h + (size_t)N * H;        // [N,H] z and t aliased in-place
  float* pooled = zt + (size_t)N * H;       // [G,H]
  float* sums   = pooled + (size_t)G * H;   // [H]
  float* sumsq  = sums + H;                 // [H]
  float* scale  = sumsq + H;                // [H]
  float* shift  = scale + H;                // [H]
  int*   cnt      = (int*)(shift + H);      // [N]
  int*   off      = cnt + N;                // [N+1]
  int*   cursor   = off + N + 1;            // [N]
  int*   perm     = cursor + N;             // [E]
  int*   src_perm = perm + E;               // [E]
  int*   bsum     = src_perm + E;           // [nb]
  int*   bbase    = bsum + 1024;            // [nb]

  int nb = (N + 255) / 256;                 // 196 <= 1024

  // --- CSR build (every launch; deterministic) ---
  hipMemsetAsync(cnt, 0, (size_t)N * sizeof(int), stream);
  count_deg<<<(E + 255) / 256, 256, 0, stream>>>(dst, cnt, E);
  block_sum<<<nb, 256, 0, stream>>>(cnt, bsum, N);
  scan_bsum<<<1, 1024, 0, stream>>>(bsum, bbase, nb);
  scan_pass<<<nb, 256, 0, stream>>>(cnt, bbase, off, cursor, N);
  scatter_csr<<<(E + 255) / 256, 256, 0, stream>>>(src, dst, cursor, perm, src_perm, E);

  node_enc<<<N, 128, 0, stream>>>(x, node_w, node_b, h, N);

  int mblk = (N + TM - 1) / TM;
  int ablk = (N + 3) / 4;
  for (int l = 0; l < 3; ++l) {
    hipMemsetAsync(sums, 0, 2 * H * sizeof(float), stream);
    aggr_csr<<<ablk, 256, 0, stream>>>(edge_attr, edge_w, edge_b, perm, src_perm,
                                       off, h, zt, N);
    mlp1<<<mblk, 256, 0, stream>>>(zt, lin1_w + (size_t)l * H * H,
                                   lin1_b + (size_t)l * H, zt, sums, sumsq, N);
    bn_finalize<<<1, H, 0, stream>>>(sums, sumsq, bn_g + (size_t)l * H,
                                     bn_b + (size_t)l * H, scale, shift, 1.0f / N);
    bool last = (l == 2);
    if (last) hipMemsetAsync(pooled, 0, (size_t)G * H * sizeof(float), stream);
    mlp2<<<mblk, 256, 0, stream>>>(zt, scale, shift, lin2_w + (size_t)l * H * H,
                                   lin2_b + (size_t)l * H, h, N,
                                   batch, last ? pooled : nullptr);
  }

  fc_kernel<<<G, 128, 0, stream>>>(pooled, fc_w, fc_b, (float*)d_out, C);
}